// Round 6
// baseline (1140.436 us; speedup 1.0000x reference)
//
#include <hip/hip_runtime.h>
#include <hip/hip_bf16.h>

#define N_NODES 50000
#define N_REL   4
#define N_EDGES 500000
#define EMB     128
#define HID     128
#define OUTD    64
#define NC      8            // atomic-spread replicas

// ---- 1) count: degrees into NC replicated counters; record in-rank ---------
__global__ void count_kernel(const int* __restrict__ src, const int* __restrict__ dst,
                             int* __restrict__ cnt_out, int* __restrict__ cnt_in,
                             int* __restrict__ rank) {
    int e = blockIdx.x * blockDim.x + threadIdx.x;
    int r = blockIdx.y;
    if (e >= N_EDGES) return;
    int c = blockIdx.x & (NC - 1);
    size_t base = ((size_t)c * N_REL + r) * N_NODES;
    rank[(size_t)r * N_EDGES + e] = atomicAdd(&cnt_in[base + dst[(size_t)r * N_EDGES + e]], 1);
    atomicAdd(&cnt_out[base + src[(size_t)r * N_EDGES + e]], 1);
}

// ---- 2) exclusive scan of total deg_in -> offs (one block per relation) ----
__global__ __launch_bounds__(1024) void scan_kernel(const int* __restrict__ cnt_in,
                                                    int* __restrict__ offs) {
    __shared__ int sh[1024];
    const int r = blockIdx.x;
    const int t = threadIdx.x;
    const int CH = 49;                          // 49*1024 >= 50001
    const int start = t * CH;
    int sum = 0;
    for (int j = start; j < start + CH; ++j)
        if (j < N_NODES) {
            int s = 0;
#pragma unroll
            for (int c = 0; c < NC; ++c)
                s += cnt_in[((size_t)c * N_REL + r) * N_NODES + j];
            sum += s;
        }
    sh[t] = sum;
    __syncthreads();
    for (int off = 1; off < 1024; off <<= 1) {
        int v = (t >= off) ? sh[t - off] : 0;
        __syncthreads();
        sh[t] += v;
        __syncthreads();
    }
    int run = sh[t] - sum;
    for (int j = start; j < start + CH; ++j) {
        if (j <= N_NODES) {
            offs[r * (N_NODES + 1) + j] = run;
            if (j < N_NODES) {
                int s = 0;
#pragma unroll
                for (int c = 0; c < NC; ++c)
                    s += cnt_in[((size_t)c * N_REL + r) * N_NODES + j];
                run += s;
            }
        }
    }
}

// ---- 3) cursors + norms in one sweep ---------------------------------------
__global__ void cursor_norm_kernel(const int* __restrict__ cnt_out,
                                   const int* __restrict__ cnt_in,
                                   const int* __restrict__ offs,
                                   float* __restrict__ nsrc, float* __restrict__ ndst,
                                   int* __restrict__ cursor) {
    int i = blockIdx.x * blockDim.x + threadIdx.x;
    if (i >= N_REL * N_NODES) return;
    int r = i / N_NODES, n = i - r * N_NODES;
    int so = 0;
#pragma unroll
    for (int c = 0; c < NC; ++c) so += cnt_out[(size_t)c * N_REL * N_NODES + i];
    nsrc[i] = so > 0 ? rsqrtf((float)so) : 0.0f;
    int run = offs[r * (N_NODES + 1) + n];
    int base = run;
#pragma unroll
    for (int c = 0; c < NC; ++c) {
        cursor[(size_t)c * N_REL * N_NODES + i] = run;
        run += cnt_in[(size_t)c * N_REL * N_NODES + i];
    }
    int si = run - base;
    ndst[i] = si > 0 ? rsqrtf((float)si) : 0.0f;
}

// ---- 4) place edges (NO atomics): p = cursor[c][r][dst] + rank -------------
__global__ void place_kernel(const int* __restrict__ src, const int* __restrict__ dst,
                             const int* __restrict__ rank,
                             const float* __restrict__ nsrc,
                             const int* __restrict__ cursor, int2* __restrict__ csr_rec) {
    int e = blockIdx.x * blockDim.x + threadIdx.x;
    int r = blockIdx.y;
    if (e >= N_EDGES) return;
    int c = blockIdx.x & (NC - 1);
    int s = src[(size_t)r * N_EDGES + e];
    int d = dst[(size_t)r * N_EDGES + e];
    int p = cursor[((size_t)c * N_REL + r) * N_NODES + d] + rank[(size_t)r * N_EDGES + e];
    csr_rec[(size_t)r * N_EDGES + p] = make_int2(s, __float_as_int(nsrc[(size_t)r * N_NODES + s]));
}

// ---- 5) gather1: one wave per dst node, sequential relations, 4-edge unroll -
__global__ __launch_bounds__(256) void gather1_kernel(
    const float* __restrict__ x,              // [N][128]
    const int2* __restrict__ csr_rec,         // [R][E]
    const int* __restrict__ offs,             // [R][N+1]
    const float* __restrict__ ndst,           // [R][N]
    float* __restrict__ agg,                  // [N][512]
    int node0, int nnodes) {
    int wid = (blockIdx.x * 256 + threadIdx.x) >> 6;
    int lane = threadIdx.x & 63;
    if (wid >= nnodes) return;
    int d = node0 + wid;
    const float2* x2 = (const float2*)x;      // row = 64 float2
    float2* arow = (float2*)(agg + (size_t)wid * (N_REL * EMB));
#pragma unroll
    for (int r = 0; r < N_REL; ++r) {
        int e = offs[r * (N_NODES + 1) + d];
        int e1 = offs[r * (N_NODES + 1) + d + 1];
        const int2* rec = csr_rec + (size_t)r * N_EDGES;
        float ax = 0.0f, ay = 0.0f;
        for (; e + 3 < e1; e += 4) {
            int2 rc0 = rec[e], rc1 = rec[e + 1], rc2 = rec[e + 2], rc3 = rec[e + 3];
            float2 v0 = x2[(size_t)rc0.x * 64 + lane];
            float2 v1 = x2[(size_t)rc1.x * 64 + lane];
            float2 v2 = x2[(size_t)rc2.x * 64 + lane];
            float2 v3 = x2[(size_t)rc3.x * 64 + lane];
            float w0 = __int_as_float(rc0.y), w1 = __int_as_float(rc1.y);
            float w2 = __int_as_float(rc2.y), w3 = __int_as_float(rc3.y);
            ax += v0.x * w0 + v1.x * w1 + v2.x * w2 + v3.x * w3;
            ay += v0.y * w0 + v1.y * w1 + v2.y * w2 + v3.y * w3;
        }
        for (; e < e1; ++e) {
            int2 rc = rec[e];
            float w = __int_as_float(rc.y);
            float2 v = x2[(size_t)rc.x * 64 + lane];
            ax += v.x * w;
            ay += v.y * w;
        }
        float sc = 0.25f * ndst[(size_t)r * N_NODES + d];
        float2 o; o.x = ax * sc; o.y = ay * sc;
        arow[r * 64 + lane] = o;
    }
}

// ---- 6) gemm1: h1[n][128] = agg[n][512] @ W1flat + 0.25*sum_r b1_r ----------
__global__ __launch_bounds__(256) void gemm1_kernel(
    const float* __restrict__ agg, const float* __restrict__ W,   // [512][128]
    const float* __restrict__ b1,                                 // [4][128]
    float* __restrict__ h1, int node0, int nnodes) {
    constexpr int K = 512, HO = 128, KT = 32;
    __shared__ float xt[64][33];
    __shared__ float wt[KT][HO];
    const int t = threadIdx.x;
    const int tx = t & 15, ty = t >> 4;         // 16x16 thread grid
    const int row0 = blockIdx.x * 64;
    float acc[4][8] = {};
    for (int k0 = 0; k0 < K; k0 += KT) {
#pragma unroll
        for (int q = 0; q < 2; ++q) {           // X tile: 512 float4
            int idx = t + q * 256;
            int row = idx >> 3, c4 = idx & 7;
            float4 v = {};
            if (row0 + row < nnodes)
                v = *(const float4*)&agg[(size_t)(row0 + row) * K + k0 + c4 * 4];
            xt[row][c4 * 4 + 0] = v.x;
            xt[row][c4 * 4 + 1] = v.y;
            xt[row][c4 * 4 + 2] = v.z;
            xt[row][c4 * 4 + 3] = v.w;
        }
#pragma unroll
        for (int q = 0; q < 4; ++q) {           // W tile: 1024 float4
            int idx = t + q * 256;
            int k = idx >> 5, c4 = idx & 31;
            *(float4*)&wt[k][c4 * 4] = *(const float4*)&W[(size_t)(k0 + k) * HO + c4 * 4];
        }
        __syncthreads();
#pragma unroll
        for (int kk = 0; kk < KT; ++kk) {
            float xv[4], wv[8];
#pragma unroll
            for (int i = 0; i < 4; ++i) xv[i] = xt[ty + 16 * i][kk];
#pragma unroll
            for (int j = 0; j < 8; ++j) wv[j] = wt[kk][tx + 16 * j];
#pragma unroll
            for (int i = 0; i < 4; ++i)
#pragma unroll
                for (int j = 0; j < 8; ++j) acc[i][j] += xv[i] * wv[j];
        }
        __syncthreads();
    }
#pragma unroll
    for (int j = 0; j < 8; ++j) {
        int c = tx + 16 * j;
        float bv = 0.25f * (b1[c] + b1[HO + c] + b1[2 * HO + c] + b1[3 * HO + c]);
#pragma unroll
        for (int i = 0; i < 4; ++i) {
            int row = row0 + ty + 16 * i;
            if (row < nnodes)
                h1[(size_t)(node0 + row) * HO + c] = acc[i][j] + bv;
        }
    }
}

// ---- 7) gemm2: p2[n][cb*128+c] = ns_{r(c)}[n] * (h1[n] @ W2cat)[c] ----------
__global__ __launch_bounds__(256) void gemm2_kernel(
    const float* __restrict__ h1,             // [N][128]
    const float* __restrict__ W2,             // [4][128][64]
    const float* __restrict__ nsrc,           // [4][N]
    float* __restrict__ p2) {                 // [N][256]
    constexpr int K = 128, KT = 32;
    __shared__ float xt[64][33];
    __shared__ float wt[KT][128];
    const int t = threadIdx.x;
    const int tx = t & 15, ty = t >> 4;
    const int row0 = blockIdx.x * 64;
    const int cb = blockIdx.y;                  // 0 or 1
    float acc[4][8] = {};
    for (int k0 = 0; k0 < K; k0 += KT) {
#pragma unroll
        for (int q = 0; q < 2; ++q) {           // X tile
            int idx = t + q * 256;
            int row = idx >> 3, c4 = idx & 7;
            float4 v = {};
            if (row0 + row < N_NODES)
                v = *(const float4*)&h1[(size_t)(row0 + row) * K + k0 + c4 * 4];
            xt[row][c4 * 4 + 0] = v.x;
            xt[row][c4 * 4 + 1] = v.y;
            xt[row][c4 * 4 + 2] = v.z;
            xt[row][c4 * 4 + 3] = v.w;
        }
#pragma unroll
        for (int q = 0; q < 4; ++q) {           // W tile: cols cb*128..+127
            int idx = t + q * 256;
            int k = idx >> 5, c4 = idx & 31;
            int r = cb * 2 + (c4 >> 4);
            int col = (c4 * 4) & 63;
            *(float4*)&wt[k][c4 * 4] =
                *(const float4*)&W2[((size_t)r * K + k0 + k) * 64 + col];
        }
        __syncthreads();
#pragma unroll
        for (int kk = 0; kk < KT; ++kk) {
            float xv[4], wv[8];
#pragma unroll
            for (int i = 0; i < 4; ++i) xv[i] = xt[ty + 16 * i][kk];
#pragma unroll
            for (int j = 0; j < 8; ++j) wv[j] = wt[kk][tx + 16 * j];
#pragma unroll
            for (int i = 0; i < 4; ++i)
#pragma unroll
                for (int j = 0; j < 8; ++j) acc[i][j] += xv[i] * wv[j];
        }
        __syncthreads();
    }
#pragma unroll
    for (int i = 0; i < 4; ++i) {
        int row = row0 + ty + 16 * i;
        if (row < N_NODES) {
            float ns0 = nsrc[(size_t)(cb * 2 + 0) * N_NODES + row];
            float ns1 = nsrc[(size_t)(cb * 2 + 1) * N_NODES + row];
#pragma unroll
            for (int j = 0; j < 8; ++j) {
                int c = tx + 16 * j;
                float s = (c < 64) ? ns0 : ns1;
                p2[(size_t)row * 256 + cb * 128 + c] = acc[i][j] * s;
            }
        }
    }
}

// ---- 8) gather2: sequential relations, 4-edge unroll ------------------------
__global__ __launch_bounds__(256) void gather2_kernel(
    const float* __restrict__ p2,             // [N][256]
    const int2* __restrict__ csr_rec,
    const int* __restrict__ offs,
    const float* __restrict__ ndst,
    const float* __restrict__ b2,             // [4][64]
    float* __restrict__ out) {
    int wid = (blockIdx.x * 256 + threadIdx.x) >> 6;
    int lane = threadIdx.x & 63;
    if (wid >= N_NODES) return;
    int d = wid;
    float res = 0.0f;
#pragma unroll
    for (int r = 0; r < N_REL; ++r) {
        int e = offs[r * (N_NODES + 1) + d];
        int e1 = offs[r * (N_NODES + 1) + d + 1];
        const int2* rec = csr_rec + (size_t)r * N_EDGES;
        const float* col = p2 + r * 64 + lane;
        float a = 0.0f;
        for (; e + 3 < e1; e += 4) {
            int2 rc0 = rec[e], rc1 = rec[e + 1], rc2 = rec[e + 2], rc3 = rec[e + 3];
            float v0 = col[(size_t)rc0.x * 256];
            float v1 = col[(size_t)rc1.x * 256];
            float v2 = col[(size_t)rc2.x * 256];
            float v3 = col[(size_t)rc3.x * 256];
            a += (v0 + v1) + (v2 + v3);
        }
        for (; e < e1; ++e)
            a += col[(size_t)rec[e].x * 256];
        res += a * ndst[(size_t)r * N_NODES + d];
    }
    res = 0.25f * res + 0.25f * (b2[lane] + b2[64 + lane] + b2[128 + lane] + b2[192 + lane]);
    out[(size_t)d * OUTD + lane] = res;
}

// ----------------------------------------------------------------- launch ---
extern "C" void kernel_launch(void* const* d_in, const int* in_sizes, int n_in,
                              void* d_out, int out_size, void* d_ws, size_t ws_size,
                              hipStream_t stream) {
    const int* src = (const int*)d_in[1];
    const int* dst = (const int*)d_in[2];
    const float* emb = (const float*)d_in[3];
    const float* W1 = (const float*)d_in[4];
    const float* b1 = (const float*)d_in[5];
    const float* W2 = (const float*)d_in[6];
    const float* b2 = (const float*)d_in[7];
    float* out = (float*)d_out;

    char* p = (char*)d_ws;
    auto alloc = [&](size_t bytes) -> void* {
        void* q = (void*)p;
        p += (bytes + 255) & ~(size_t)255;
        return q;
    };
    int* cnt_out = (int*)alloc((size_t)NC * N_REL * N_NODES * 4);   // 6.4 MB
    int* cnt_in  = (int*)alloc((size_t)NC * N_REL * N_NODES * 4);   // 6.4 MB
    int* rank    = (int*)alloc((size_t)N_REL * N_EDGES * 4);        // 8 MB
    int* offs = (int*)alloc((size_t)N_REL * (N_NODES + 1) * 4);
    int* cursor = (int*)alloc((size_t)NC * N_REL * N_NODES * 4);    // 6.4 MB
    int2* csr_rec = (int2*)alloc((size_t)N_REL * N_EDGES * 8);      // 16 MB
    float* nsrc = (float*)alloc((size_t)N_REL * N_NODES * 4);
    float* ndst = (float*)alloc((size_t)N_REL * N_NODES * 4);
    float* h1 = (float*)alloc((size_t)N_NODES * HID * 4);           // 25.6 MB
    float* p2 = (float*)alloc((size_t)N_NODES * 256 * 4);           // 51.2 MB
    size_t used = (size_t)(p - (char*)d_ws);
    size_t avail = ws_size > used ? ws_size - used : 0;
    size_t maxn = avail / (512 * 4);
    int npc = (int)(maxn > (size_t)N_NODES ? (size_t)N_NODES : maxn);
    if (npc < 256) npc = 256;
    float* agg = (float*)p;

    hipMemsetAsync(cnt_out, 0, (size_t)2 * NC * N_REL * N_NODES * 4, stream);
    dim3 egrid((N_EDGES + 255) / 256, N_REL);
    count_kernel<<<egrid, 256, 0, stream>>>(src, dst, cnt_out, cnt_in, rank);
    scan_kernel<<<N_REL, 1024, 0, stream>>>(cnt_in, offs);
    cursor_norm_kernel<<<(N_REL * N_NODES + 255) / 256, 256, 0, stream>>>(
        cnt_out, cnt_in, offs, nsrc, ndst, cursor);
    place_kernel<<<egrid, 256, 0, stream>>>(src, dst, rank, nsrc, cursor, csr_rec);

    // layer 1: emb -> agg(chunked) -> h1
    for (int n0 = 0; n0 < N_NODES; n0 += npc) {
        int nn = (N_NODES - n0) < npc ? (N_NODES - n0) : npc;
        gather1_kernel<<<(nn + 3) / 4, 256, 0, stream>>>(emb, csr_rec, offs, ndst, agg, n0, nn);
        gemm1_kernel<<<(nn + 63) / 64, 256, 0, stream>>>(agg, W1, b1, h1, n0, nn);
    }
    // layer 2: h1 -> p2 (project-first, all relations) -> out
    dim3 g2grid((N_NODES + 63) / 64, 2);
    gemm2_kernel<<<g2grid, 256, 0, stream>>>(h1, W2, nsrc, p2);
    gather2_kernel<<<(N_NODES * 64 + 255) / 256, 256, 0, stream>>>(
        p2, csr_rec, offs, ndst, b2, out);
}

// Round 7
// 678.804 us; speedup vs baseline: 1.6801x; 1.6801x over previous
//
#include <hip/hip_runtime.h>
#include <hip/hip_bf16.h>

#define N_NODES 50000
#define N_REL   4
#define N_EDGES 500000
#define EMB     128
#define HID     128
#define OUTD    64
#define NC      8            // atomic-spread replicas
#define NBLK    196          // ceil(N_NODES/256)

// ---- 1) count: degrees into NC replicated counters; record in-rank ---------
__global__ void count_kernel(const int* __restrict__ src, const int* __restrict__ dst,
                             int* __restrict__ cnt_out, int* __restrict__ cnt_in,
                             int* __restrict__ rank) {
    int e = blockIdx.x * blockDim.x + threadIdx.x;
    int r = blockIdx.y;
    if (e >= N_EDGES) return;
    int c = blockIdx.x & (NC - 1);
    size_t base = ((size_t)c * N_REL + r) * N_NODES;
    rank[(size_t)r * N_EDGES + e] = atomicAdd(&cnt_in[base + dst[(size_t)r * N_EDGES + e]], 1);
    atomicAdd(&cnt_out[base + src[(size_t)r * N_EDGES + e]], 1);
}

// ---- 2a) scan1: copy-reduce + norms + per-block exclusive scan -------------
__global__ __launch_bounds__(256) void scan1_kernel(
    const int* __restrict__ cnt_out, const int* __restrict__ cnt_in,
    float* __restrict__ nsrc, float* __restrict__ ndst,
    int* __restrict__ offs, int* __restrict__ bsum) {
    const int r = blockIdx.y;
    const int blk = blockIdx.x;
    const int t = threadIdx.x;
    const int node = blk * 256 + t;
    int din = 0, dout = 0;
    if (node < N_NODES) {
        size_t idx = (size_t)r * N_NODES + node;
#pragma unroll
        for (int c = 0; c < NC; ++c) {
            din  += cnt_in [(size_t)c * N_REL * N_NODES + idx];
            dout += cnt_out[(size_t)c * N_REL * N_NODES + idx];
        }
        nsrc[idx] = dout > 0 ? rsqrtf((float)dout) : 0.0f;
        ndst[idx] = din  > 0 ? rsqrtf((float)din)  : 0.0f;
    }
    __shared__ int sh[256];
    sh[t] = din;
    __syncthreads();
#pragma unroll
    for (int off = 1; off < 256; off <<= 1) {
        int v = (t >= off) ? sh[t - off] : 0;
        __syncthreads();
        sh[t] += v;
        __syncthreads();
    }
    if (node < N_NODES) offs[r * (N_NODES + 1) + node] = sh[t] - din;  // exclusive (block-local)
    if (t == 255) bsum[r * NBLK + blk] = sh[255];
}

// ---- 2b) scan2: scan block sums (196 per relation) --------------------------
__global__ __launch_bounds__(256) void scan2_kernel(int* __restrict__ bsum,
                                                    int* __restrict__ offs) {
    const int r = blockIdx.x;
    const int t = threadIdx.x;
    __shared__ int sh[256];
    int v = (t < NBLK) ? bsum[r * NBLK + t] : 0;
    sh[t] = v;
    __syncthreads();
#pragma unroll
    for (int off = 1; off < 256; off <<= 1) {
        int u = (t >= off) ? sh[t - off] : 0;
        __syncthreads();
        sh[t] += u;
        __syncthreads();
    }
    if (t < NBLK) bsum[r * NBLK + t] = sh[t] - v;   // exclusive block base
    if (t == 0) offs[r * (N_NODES + 1) + N_NODES] = N_EDGES;
}

// ---- 2c) finalize offs + per-copy cursors -----------------------------------
__global__ void cursor_fin_kernel(const int* __restrict__ cnt_in,
                                  const int* __restrict__ bsum,
                                  int* __restrict__ offs, int* __restrict__ cursor) {
    int i = blockIdx.x * blockDim.x + threadIdx.x;
    if (i >= N_REL * N_NODES) return;
    int r = i / N_NODES, n = i - r * N_NODES;
    int off = offs[r * (N_NODES + 1) + n] + bsum[r * NBLK + (n >> 8)];
    offs[r * (N_NODES + 1) + n] = off;
    int run = off;
#pragma unroll
    for (int c = 0; c < NC; ++c) {
        cursor[(size_t)c * N_REL * N_NODES + i] = run;
        run += cnt_in[(size_t)c * N_REL * N_NODES + i];
    }
}

// ---- 3) place edges (NO atomics): p = cursor[c][r][dst] + rank -------------
__global__ void place_kernel(const int* __restrict__ src, const int* __restrict__ dst,
                             const int* __restrict__ rank,
                             const float* __restrict__ nsrc,
                             const int* __restrict__ cursor, int2* __restrict__ csr_rec) {
    int e = blockIdx.x * blockDim.x + threadIdx.x;
    int r = blockIdx.y;
    if (e >= N_EDGES) return;
    int c = blockIdx.x & (NC - 1);
    int s = src[(size_t)r * N_EDGES + e];
    int d = dst[(size_t)r * N_EDGES + e];
    int p = cursor[((size_t)c * N_REL + r) * N_NODES + d] + rank[(size_t)r * N_EDGES + e];
    csr_rec[(size_t)r * N_EDGES + p] = make_int2(s, __float_as_int(nsrc[(size_t)r * N_NODES + s]));
}

// ---- 4) gather1: one wave per dst node, sequential relations, 4-edge unroll -
__global__ __launch_bounds__(256) void gather1_kernel(
    const float* __restrict__ x,              // [N][128]
    const int2* __restrict__ csr_rec,         // [R][E]
    const int* __restrict__ offs,             // [R][N+1]
    const float* __restrict__ ndst,           // [R][N]
    float* __restrict__ agg,                  // [N][512]
    int node0, int nnodes) {
    int wid = (blockIdx.x * 256 + threadIdx.x) >> 6;
    int lane = threadIdx.x & 63;
    if (wid >= nnodes) return;
    int d = node0 + wid;
    const float2* x2 = (const float2*)x;      // row = 64 float2
    float2* arow = (float2*)(agg + (size_t)wid * (N_REL * EMB));
#pragma unroll
    for (int r = 0; r < N_REL; ++r) {
        int e = offs[r * (N_NODES + 1) + d];
        int e1 = offs[r * (N_NODES + 1) + d + 1];
        const int2* rec = csr_rec + (size_t)r * N_EDGES;
        float ax = 0.0f, ay = 0.0f;
        for (; e + 3 < e1; e += 4) {
            int2 rc0 = rec[e], rc1 = rec[e + 1], rc2 = rec[e + 2], rc3 = rec[e + 3];
            float2 v0 = x2[(size_t)rc0.x * 64 + lane];
            float2 v1 = x2[(size_t)rc1.x * 64 + lane];
            float2 v2 = x2[(size_t)rc2.x * 64 + lane];
            float2 v3 = x2[(size_t)rc3.x * 64 + lane];
            float w0 = __int_as_float(rc0.y), w1 = __int_as_float(rc1.y);
            float w2 = __int_as_float(rc2.y), w3 = __int_as_float(rc3.y);
            ax += v0.x * w0 + v1.x * w1 + v2.x * w2 + v3.x * w3;
            ay += v0.y * w0 + v1.y * w1 + v2.y * w2 + v3.y * w3;
        }
        for (; e < e1; ++e) {
            int2 rc = rec[e];
            float w = __int_as_float(rc.y);
            float2 v = x2[(size_t)rc.x * 64 + lane];
            ax += v.x * w;
            ay += v.y * w;
        }
        float sc = 0.25f * ndst[(size_t)r * N_NODES + d];
        float2 o; o.x = ax * sc; o.y = ay * sc;
        arow[r * 64 + lane] = o;
    }
}

// ---- 5) gemm1: h1[n][128] = agg[n][512] @ W1flat + 0.25*sum_r b1_r ----------
__global__ __launch_bounds__(256) void gemm1_kernel(
    const float* __restrict__ agg, const float* __restrict__ W,   // [512][128]
    const float* __restrict__ b1,                                 // [4][128]
    float* __restrict__ h1, int node0, int nnodes) {
    constexpr int K = 512, HO = 128, KT = 32;
    __shared__ float xt[64][33];
    __shared__ float wt[KT][HO];
    const int t = threadIdx.x;
    const int tx = t & 15, ty = t >> 4;         // 16x16 thread grid
    const int row0 = blockIdx.x * 64;
    float acc[4][8] = {};
    for (int k0 = 0; k0 < K; k0 += KT) {
#pragma unroll
        for (int q = 0; q < 2; ++q) {           // X tile: 512 float4
            int idx = t + q * 256;
            int row = idx >> 3, c4 = idx & 7;
            float4 v = {};
            if (row0 + row < nnodes)
                v = *(const float4*)&agg[(size_t)(row0 + row) * K + k0 + c4 * 4];
            xt[row][c4 * 4 + 0] = v.x;
            xt[row][c4 * 4 + 1] = v.y;
            xt[row][c4 * 4 + 2] = v.z;
            xt[row][c4 * 4 + 3] = v.w;
        }
#pragma unroll
        for (int q = 0; q < 4; ++q) {           // W tile: 1024 float4
            int idx = t + q * 256;
            int k = idx >> 5, c4 = idx & 31;
            *(float4*)&wt[k][c4 * 4] = *(const float4*)&W[(size_t)(k0 + k) * HO + c4 * 4];
        }
        __syncthreads();
#pragma unroll
        for (int kk = 0; kk < KT; ++kk) {
            float xv[4], wv[8];
#pragma unroll
            for (int i = 0; i < 4; ++i) xv[i] = xt[ty + 16 * i][kk];
#pragma unroll
            for (int j = 0; j < 8; ++j) wv[j] = wt[kk][tx + 16 * j];
#pragma unroll
            for (int i = 0; i < 4; ++i)
#pragma unroll
                for (int j = 0; j < 8; ++j) acc[i][j] += xv[i] * wv[j];
        }
        __syncthreads();
    }
#pragma unroll
    for (int j = 0; j < 8; ++j) {
        int c = tx + 16 * j;
        float bv = 0.25f * (b1[c] + b1[HO + c] + b1[2 * HO + c] + b1[3 * HO + c]);
#pragma unroll
        for (int i = 0; i < 4; ++i) {
            int row = row0 + ty + 16 * i;
            if (row < nnodes)
                h1[(size_t)(node0 + row) * HO + c] = acc[i][j] + bv;
        }
    }
}

// ---- 6) gemm2: p2[n][cb*128+c] = ns_{r(c)}[n] * (h1[n] @ W2cat)[c] ----------
__global__ __launch_bounds__(256) void gemm2_kernel(
    const float* __restrict__ h1,             // [N][128]
    const float* __restrict__ W2,             // [4][128][64]
    const float* __restrict__ nsrc,           // [4][N]
    float* __restrict__ p2) {                 // [N][256]
    constexpr int K = 128, KT = 32;
    __shared__ float xt[64][33];
    __shared__ float wt[KT][128];
    const int t = threadIdx.x;
    const int tx = t & 15, ty = t >> 4;
    const int row0 = blockIdx.x * 64;
    const int cb = blockIdx.y;                  // 0 or 1
    float acc[4][8] = {};
    for (int k0 = 0; k0 < K; k0 += KT) {
#pragma unroll
        for (int q = 0; q < 2; ++q) {           // X tile
            int idx = t + q * 256;
            int row = idx >> 3, c4 = idx & 7;
            float4 v = {};
            if (row0 + row < N_NODES)
                v = *(const float4*)&h1[(size_t)(row0 + row) * K + k0 + c4 * 4];
            xt[row][c4 * 4 + 0] = v.x;
            xt[row][c4 * 4 + 1] = v.y;
            xt[row][c4 * 4 + 2] = v.z;
            xt[row][c4 * 4 + 3] = v.w;
        }
#pragma unroll
        for (int q = 0; q < 4; ++q) {           // W tile: cols cb*128..+127
            int idx = t + q * 256;
            int k = idx >> 5, c4 = idx & 31;
            int r = cb * 2 + (c4 >> 4);
            int col = (c4 * 4) & 63;
            *(float4*)&wt[k][c4 * 4] =
                *(const float4*)&W2[((size_t)r * K + k0 + k) * 64 + col];
        }
        __syncthreads();
#pragma unroll
        for (int kk = 0; kk < KT; ++kk) {
            float xv[4], wv[8];
#pragma unroll
            for (int i = 0; i < 4; ++i) xv[i] = xt[ty + 16 * i][kk];
#pragma unroll
            for (int j = 0; j < 8; ++j) wv[j] = wt[kk][tx + 16 * j];
#pragma unroll
            for (int i = 0; i < 4; ++i)
#pragma unroll
                for (int j = 0; j < 8; ++j) acc[i][j] += xv[i] * wv[j];
        }
        __syncthreads();
    }
#pragma unroll
    for (int i = 0; i < 4; ++i) {
        int row = row0 + ty + 16 * i;
        if (row < N_NODES) {
            float ns0 = nsrc[(size_t)(cb * 2 + 0) * N_NODES + row];
            float ns1 = nsrc[(size_t)(cb * 2 + 1) * N_NODES + row];
#pragma unroll
            for (int j = 0; j < 8; ++j) {
                int c = tx + 16 * j;
                float s = (c < 64) ? ns0 : ns1;
                p2[(size_t)row * 256 + cb * 128 + c] = acc[i][j] * s;
            }
        }
    }
}

// ---- 7) gather2: sequential relations, 4-edge unroll ------------------------
__global__ __launch_bounds__(256) void gather2_kernel(
    const float* __restrict__ p2,             // [N][256]
    const int2* __restrict__ csr_rec,
    const int* __restrict__ offs,
    const float* __restrict__ ndst,
    const float* __restrict__ b2,             // [4][64]
    float* __restrict__ out) {
    int wid = (blockIdx.x * 256 + threadIdx.x) >> 6;
    int lane = threadIdx.x & 63;
    if (wid >= N_NODES) return;
    int d = wid;
    float res = 0.0f;
#pragma unroll
    for (int r = 0; r < N_REL; ++r) {
        int e = offs[r * (N_NODES + 1) + d];
        int e1 = offs[r * (N_NODES + 1) + d + 1];
        const int2* rec = csr_rec + (size_t)r * N_EDGES;
        const float* col = p2 + r * 64 + lane;
        float a = 0.0f;
        for (; e + 3 < e1; e += 4) {
            int2 rc0 = rec[e], rc1 = rec[e + 1], rc2 = rec[e + 2], rc3 = rec[e + 3];
            float v0 = col[(size_t)rc0.x * 256];
            float v1 = col[(size_t)rc1.x * 256];
            float v2 = col[(size_t)rc2.x * 256];
            float v3 = col[(size_t)rc3.x * 256];
            a += (v0 + v1) + (v2 + v3);
        }
        for (; e < e1; ++e)
            a += col[(size_t)rec[e].x * 256];
        res += a * ndst[(size_t)r * N_NODES + d];
    }
    res = 0.25f * res + 0.25f * (b2[lane] + b2[64 + lane] + b2[128 + lane] + b2[192 + lane]);
    out[(size_t)d * OUTD + lane] = res;
}

// ----------------------------------------------------------------- launch ---
extern "C" void kernel_launch(void* const* d_in, const int* in_sizes, int n_in,
                              void* d_out, int out_size, void* d_ws, size_t ws_size,
                              hipStream_t stream) {
    const int* src = (const int*)d_in[1];
    const int* dst = (const int*)d_in[2];
    const float* emb = (const float*)d_in[3];
    const float* W1 = (const float*)d_in[4];
    const float* b1 = (const float*)d_in[5];
    const float* W2 = (const float*)d_in[6];
    const float* b2 = (const float*)d_in[7];
    float* out = (float*)d_out;

    char* p = (char*)d_ws;
    auto alloc = [&](size_t bytes) -> void* {
        void* q = (void*)p;
        p += (bytes + 255) & ~(size_t)255;
        return q;
    };
    int* cnt_out = (int*)alloc((size_t)NC * N_REL * N_NODES * 4);   // 6.4 MB
    int* cnt_in  = (int*)alloc((size_t)NC * N_REL * N_NODES * 4);   // 6.4 MB
    int* rank    = (int*)alloc((size_t)N_REL * N_EDGES * 4);        // 8 MB
    int* offs = (int*)alloc((size_t)N_REL * (N_NODES + 1) * 4);
    int* bsum = (int*)alloc((size_t)N_REL * NBLK * 4);
    int* cursor = (int*)alloc((size_t)NC * N_REL * N_NODES * 4);    // 6.4 MB
    int2* csr_rec = (int2*)alloc((size_t)N_REL * N_EDGES * 8);      // 16 MB
    float* nsrc = (float*)alloc((size_t)N_REL * N_NODES * 4);
    float* ndst = (float*)alloc((size_t)N_REL * N_NODES * 4);
    float* h1 = (float*)alloc((size_t)N_NODES * HID * 4);           // 25.6 MB
    float* p2 = (float*)alloc((size_t)N_NODES * 256 * 4);           // 51.2 MB
    size_t used = (size_t)(p - (char*)d_ws);
    size_t avail = ws_size > used ? ws_size - used : 0;
    size_t maxn = avail / (512 * 4);
    int npc = (int)(maxn > (size_t)N_NODES ? (size_t)N_NODES : maxn);
    if (npc < 256) npc = 256;
    float* agg = (float*)p;

    hipMemsetAsync(cnt_out, 0, (size_t)2 * NC * N_REL * N_NODES * 4, stream);
    dim3 egrid((N_EDGES + 255) / 256, N_REL);
    count_kernel<<<egrid, 256, 0, stream>>>(src, dst, cnt_out, cnt_in, rank);
    dim3 sgrid(NBLK, N_REL);
    scan1_kernel<<<sgrid, 256, 0, stream>>>(cnt_out, cnt_in, nsrc, ndst, offs, bsum);
    scan2_kernel<<<N_REL, 256, 0, stream>>>(bsum, offs);
    cursor_fin_kernel<<<(N_REL * N_NODES + 255) / 256, 256, 0, stream>>>(
        cnt_in, bsum, offs, cursor);
    place_kernel<<<egrid, 256, 0, stream>>>(src, dst, rank, nsrc, cursor, csr_rec);

    // layer 1: emb -> agg(chunked) -> h1
    for (int n0 = 0; n0 < N_NODES; n0 += npc) {
        int nn = (N_NODES - n0) < npc ? (N_NODES - n0) : npc;
        gather1_kernel<<<(nn + 3) / 4, 256, 0, stream>>>(emb, csr_rec, offs, ndst, agg, n0, nn);
        gemm1_kernel<<<(nn + 63) / 64, 256, 0, stream>>>(agg, W1, b1, h1, n0, nn);
    }
    // layer 2: h1 -> p2 (project-first, all relations) -> out
    dim3 g2grid((N_NODES + 63) / 64, 2);
    gemm2_kernel<<<g2grid, 256, 0, stream>>>(h1, W2, nsrc, p2);
    gather2_kernel<<<(N_NODES * 64 + 255) / 256, 256, 0, stream>>>(
        p2, csr_rec, offs, ndst, b2, out);
}

// Round 8
// 538.126 us; speedup vs baseline: 2.1193x; 1.2614x over previous
//
#include <hip/hip_runtime.h>
#include <hip/hip_bf16.h>

#define N_NODES 50000
#define N_REL   4
#define N_EDGES 500000
#define EMB     128
#define HID     128
#define OUTD    64
#define SLICES  32
#define EPS     (N_EDGES / SLICES)   // 15625 edges per slice (exact)
#define CHUNKN  25000                // nodes per chunk (2 chunks)
#define CHUNKW  12500                // packed u32 per chunk (2 x u16)
#define NBLK2   98                   // ceil(50000 / 512) scan1 blocks per rel

// ---- 1) hist: per-slice LDS histograms, NO global atomics ------------------
// grid (SLICES, 2 chunks, 8): z<4 -> dst histogram (+rank), z>=4 -> src.
__global__ __launch_bounds__(256) void hist_kernel(
    const int* __restrict__ src, const int* __restrict__ dst,
    unsigned* __restrict__ cnt_dst, unsigned* __restrict__ cnt_src,
    unsigned short* __restrict__ rank) {
    const int s = blockIdx.x;
    const int ch = blockIdx.y;
    const int z = blockIdx.z;
    const int r = z & 3;
    const bool do_dst = (z < 4);
    const int t = threadIdx.x;
    __shared__ unsigned bins[CHUNKW];          // 50 KB: 25000 x u16 packed
    for (int i = t; i < CHUNKW; i += 256) bins[i] = 0;
    __syncthreads();
    const int* col = do_dst ? dst : src;
    const int c0 = ch * CHUNKN;
    for (int e = s * EPS + t; e < (s + 1) * EPS; e += 256) {
        int d = col[(size_t)r * N_EDGES + e];
        unsigned dl = (unsigned)(d - c0);
        if (dl < CHUNKN) {
            unsigned sh = (dl & 1) * 16;
            unsigned old = atomicAdd(&bins[dl >> 1], 1u << sh);
            if (do_dst)
                rank[(size_t)r * N_EDGES + e] = (unsigned short)((old >> sh) & 0xffffu);
        }
    }
    __syncthreads();
    unsigned* out = (do_dst ? cnt_dst : cnt_src)
                  + (((size_t)s * N_REL + r) * 2 + ch) * CHUNKW;
    for (int i = t; i < CHUNKW; i += 256) out[i] = bins[i];
}

// ---- 2a) scan1: slice-reduce + in-place slice-prefix + norms + block scan ---
// thread t handles node pair (2*pair, 2*pair+1); 512 nodes per block.
__global__ __launch_bounds__(256) void scan1_kernel(
    unsigned* __restrict__ cnt_dst, const unsigned* __restrict__ cnt_src,
    float* __restrict__ nsrc, float* __restrict__ ndst,
    int* __restrict__ offs, int* __restrict__ bsum) {
    const int r = blockIdx.y;
    const int blk = blockIdx.x;
    const int t = threadIdx.x;
    const int pair = blk * 256 + t;            // 0 .. 24999
    int d0 = 0, d1 = 0;
    if (pair < CHUNKN) {                       // 25000 pairs total
        int ch = (2 * pair) / CHUNKN;          // 0 or 1 (chunk boundary even)
        int i = pair - ch * CHUNKW;
        unsigned run0 = 0, run1 = 0;
#pragma unroll
        for (int s = 0; s < SLICES; ++s) {
            size_t idx = (((size_t)s * N_REL + r) * 2 + ch) * CHUNKW + i;
            unsigned v = cnt_dst[idx];
            cnt_dst[idx] = run0 | (run1 << 16); // exclusive slice-prefix (packed)
            run0 += v & 0xffffu;
            run1 += v >> 16;
        }
        d0 = (int)run0; d1 = (int)run1;
        unsigned s0 = 0, s1 = 0;
#pragma unroll
        for (int s = 0; s < SLICES; ++s) {
            unsigned v = cnt_src[(((size_t)s * N_REL + r) * 2 + ch) * CHUNKW + i];
            s0 += v & 0xffffu;
            s1 += v >> 16;
        }
        size_t nidx = (size_t)r * N_NODES + 2 * pair;
        nsrc[nidx]     = s0 ? rsqrtf((float)s0) : 0.0f;
        nsrc[nidx + 1] = s1 ? rsqrtf((float)s1) : 0.0f;
        ndst[nidx]     = d0 ? rsqrtf((float)d0) : 0.0f;
        ndst[nidx + 1] = d1 ? rsqrtf((float)d1) : 0.0f;
    }
    __shared__ int sh[256];
    int dsum = d0 + d1;
    sh[t] = dsum;
    __syncthreads();
#pragma unroll
    for (int off = 1; off < 256; off <<= 1) {
        int v = (t >= off) ? sh[t - off] : 0;
        __syncthreads();
        sh[t] += v;
        __syncthreads();
    }
    if (pair < CHUNKN) {
        int base = sh[t] - dsum;               // exclusive within block
        offs[r * (N_NODES + 1) + 2 * pair]     = base;
        offs[r * (N_NODES + 1) + 2 * pair + 1] = base + d0;
    }
    if (t == 255) bsum[r * NBLK2 + blk] = sh[255];
}

// ---- 2b) scan2: scan block sums (98 per relation) ---------------------------
__global__ __launch_bounds__(256) void scan2_kernel(int* __restrict__ bsum,
                                                    int* __restrict__ offs) {
    const int r = blockIdx.x;
    const int t = threadIdx.x;
    __shared__ int sh[256];
    int v = (t < NBLK2) ? bsum[r * NBLK2 + t] : 0;
    sh[t] = v;
    __syncthreads();
#pragma unroll
    for (int off = 1; off < 256; off <<= 1) {
        int u = (t >= off) ? sh[t - off] : 0;
        __syncthreads();
        sh[t] += u;
        __syncthreads();
    }
    if (t < NBLK2) bsum[r * NBLK2 + t] = sh[t] - v;   // exclusive block base
    if (t == 0) offs[r * (N_NODES + 1) + N_NODES] = N_EDGES;
}

// ---- 2c) finalize offs ------------------------------------------------------
__global__ void offs_fin_kernel(const int* __restrict__ bsum, int* __restrict__ offs) {
    int i = blockIdx.x * blockDim.x + threadIdx.x;
    if (i >= N_REL * N_NODES) return;
    int r = i / N_NODES, n = i - r * N_NODES;
    offs[r * (N_NODES + 1) + n] += bsum[r * NBLK2 + (n >> 9)];
}

// ---- 3) place edges (NO atomics): p = offs + slice_prefix + rank ------------
__global__ void place_kernel(const int* __restrict__ src, const int* __restrict__ dst,
                             const unsigned short* __restrict__ rank,
                             const unsigned* __restrict__ cnt_dst,   // slice prefixes
                             const float* __restrict__ nsrc,
                             const int* __restrict__ offs, int2* __restrict__ csr_rec) {
    int e = blockIdx.x * blockDim.x + threadIdx.x;
    int r = blockIdx.y;
    if (e >= N_EDGES) return;
    int s = e / EPS;
    int d = dst[(size_t)r * N_EDGES + e];
    int sg = src[(size_t)r * N_EDGES + e];
    int ch = d / CHUNKN;
    int dl = d - ch * CHUNKN;
    unsigned pv = cnt_dst[(((size_t)s * N_REL + r) * 2 + ch) * CHUNKW + (dl >> 1)];
    int base = (int)((pv >> ((dl & 1) * 16)) & 0xffffu);
    int p = offs[r * (N_NODES + 1) + d] + base + (int)rank[(size_t)r * N_EDGES + e];
    csr_rec[(size_t)r * N_EDGES + p] =
        make_int2(sg, __float_as_int(nsrc[(size_t)r * N_NODES + sg]));
}

// ---- 4) gather1: one wave per dst node, sequential relations, 4-edge unroll -
__global__ __launch_bounds__(256) void gather1_kernel(
    const float* __restrict__ x,              // [N][128]
    const int2* __restrict__ csr_rec,         // [R][E]
    const int* __restrict__ offs,             // [R][N+1]
    const float* __restrict__ ndst,           // [R][N]
    float* __restrict__ agg,                  // [chunk][512]
    int node0, int nnodes) {
    int wid = (blockIdx.x * 256 + threadIdx.x) >> 6;
    int lane = threadIdx.x & 63;
    if (wid >= nnodes) return;
    int d = node0 + wid;
    const float2* x2 = (const float2*)x;      // row = 64 float2
    float2* arow = (float2*)(agg + (size_t)wid * (N_REL * EMB));
#pragma unroll
    for (int r = 0; r < N_REL; ++r) {
        int e = offs[r * (N_NODES + 1) + d];
        int e1 = offs[r * (N_NODES + 1) + d + 1];
        const int2* rec = csr_rec + (size_t)r * N_EDGES;
        float ax = 0.0f, ay = 0.0f;
        for (; e + 3 < e1; e += 4) {
            int2 rc0 = rec[e], rc1 = rec[e + 1], rc2 = rec[e + 2], rc3 = rec[e + 3];
            float2 v0 = x2[(size_t)rc0.x * 64 + lane];
            float2 v1 = x2[(size_t)rc1.x * 64 + lane];
            float2 v2 = x2[(size_t)rc2.x * 64 + lane];
            float2 v3 = x2[(size_t)rc3.x * 64 + lane];
            float w0 = __int_as_float(rc0.y), w1 = __int_as_float(rc1.y);
            float w2 = __int_as_float(rc2.y), w3 = __int_as_float(rc3.y);
            ax += v0.x * w0 + v1.x * w1 + v2.x * w2 + v3.x * w3;
            ay += v0.y * w0 + v1.y * w1 + v2.y * w2 + v3.y * w3;
        }
        for (; e < e1; ++e) {
            int2 rc = rec[e];
            float w = __int_as_float(rc.y);
            float2 v = x2[(size_t)rc.x * 64 + lane];
            ax += v.x * w;
            ay += v.y * w;
        }
        float sc = 0.25f * ndst[(size_t)r * N_NODES + d];
        float2 o; o.x = ax * sc; o.y = ay * sc;
        arow[r * 64 + lane] = o;
    }
}

// ---- 5) gemm1: h1[n][128] = agg[n][512] @ W1flat + 0.25*sum_r b1_r ----------
__global__ __launch_bounds__(256) void gemm1_kernel(
    const float* __restrict__ agg, const float* __restrict__ W,   // [512][128]
    const float* __restrict__ b1,                                 // [4][128]
    float* __restrict__ h1, int node0, int nnodes) {
    constexpr int K = 512, HO = 128, KT = 32;
    __shared__ float xt[64][33];
    __shared__ float wt[KT][HO];
    const int t = threadIdx.x;
    const int tx = t & 15, ty = t >> 4;         // 16x16 thread grid
    const int row0 = blockIdx.x * 64;
    float acc[4][8] = {};
    for (int k0 = 0; k0 < K; k0 += KT) {
#pragma unroll
        for (int q = 0; q < 2; ++q) {           // X tile: 512 float4
            int idx = t + q * 256;
            int row = idx >> 3, c4 = idx & 7;
            float4 v = {};
            if (row0 + row < nnodes)
                v = *(const float4*)&agg[(size_t)(row0 + row) * K + k0 + c4 * 4];
            xt[row][c4 * 4 + 0] = v.x;
            xt[row][c4 * 4 + 1] = v.y;
            xt[row][c4 * 4 + 2] = v.z;
            xt[row][c4 * 4 + 3] = v.w;
        }
#pragma unroll
        for (int q = 0; q < 4; ++q) {           // W tile: 1024 float4
            int idx = t + q * 256;
            int k = idx >> 5, c4 = idx & 31;
            *(float4*)&wt[k][c4 * 4] = *(const float4*)&W[(size_t)(k0 + k) * HO + c4 * 4];
        }
        __syncthreads();
#pragma unroll
        for (int kk = 0; kk < KT; ++kk) {
            float xv[4], wv[8];
#pragma unroll
            for (int i = 0; i < 4; ++i) xv[i] = xt[ty + 16 * i][kk];
#pragma unroll
            for (int j = 0; j < 8; ++j) wv[j] = wt[kk][tx + 16 * j];
#pragma unroll
            for (int i = 0; i < 4; ++i)
#pragma unroll
                for (int j = 0; j < 8; ++j) acc[i][j] += xv[i] * wv[j];
        }
        __syncthreads();
    }
#pragma unroll
    for (int j = 0; j < 8; ++j) {
        int c = tx + 16 * j;
        float bv = 0.25f * (b1[c] + b1[HO + c] + b1[2 * HO + c] + b1[3 * HO + c]);
#pragma unroll
        for (int i = 0; i < 4; ++i) {
            int row = row0 + ty + 16 * i;
            if (row < nnodes)
                h1[(size_t)(node0 + row) * HO + c] = acc[i][j] + bv;
        }
    }
}

// ---- 6) gemm2: p2[n][cb*128+c] = ns_{r(c)}[n] * (h1[n] @ W2cat)[c] ----------
__global__ __launch_bounds__(256) void gemm2_kernel(
    const float* __restrict__ h1,             // [N][128]
    const float* __restrict__ W2,             // [4][128][64]
    const float* __restrict__ nsrc,           // [4][N]
    float* __restrict__ p2) {                 // [N][256]
    constexpr int K = 128, KT = 32;
    __shared__ float xt[64][33];
    __shared__ float wt[KT][128];
    const int t = threadIdx.x;
    const int tx = t & 15, ty = t >> 4;
    const int row0 = blockIdx.x * 64;
    const int cb = blockIdx.y;                  // 0 or 1
    float acc[4][8] = {};
    for (int k0 = 0; k0 < K; k0 += KT) {
#pragma unroll
        for (int q = 0; q < 2; ++q) {           // X tile
            int idx = t + q * 256;
            int row = idx >> 3, c4 = idx & 7;
            float4 v = {};
            if (row0 + row < N_NODES)
                v = *(const float4*)&h1[(size_t)(row0 + row) * K + k0 + c4 * 4];
            xt[row][c4 * 4 + 0] = v.x;
            xt[row][c4 * 4 + 1] = v.y;
            xt[row][c4 * 4 + 2] = v.z;
            xt[row][c4 * 4 + 3] = v.w;
        }
#pragma unroll
        for (int q = 0; q < 4; ++q) {           // W tile: cols cb*128..+127
            int idx = t + q * 256;
            int k = idx >> 5, c4 = idx & 31;
            int r = cb * 2 + (c4 >> 4);
            int col = (c4 * 4) & 63;
            *(float4*)&wt[k][c4 * 4] =
                *(const float4*)&W2[((size_t)r * K + k0 + k) * 64 + col];
        }
        __syncthreads();
#pragma unroll
        for (int kk = 0; kk < KT; ++kk) {
            float xv[4], wv[8];
#pragma unroll
            for (int i = 0; i < 4; ++i) xv[i] = xt[ty + 16 * i][kk];
#pragma unroll
            for (int j = 0; j < 8; ++j) wv[j] = wt[kk][tx + 16 * j];
#pragma unroll
            for (int i = 0; i < 4; ++i)
#pragma unroll
                for (int j = 0; j < 8; ++j) acc[i][j] += xv[i] * wv[j];
        }
        __syncthreads();
    }
#pragma unroll
    for (int i = 0; i < 4; ++i) {
        int row = row0 + ty + 16 * i;
        if (row < N_NODES) {
            float ns0 = nsrc[(size_t)(cb * 2 + 0) * N_NODES + row];
            float ns1 = nsrc[(size_t)(cb * 2 + 1) * N_NODES + row];
#pragma unroll
            for (int j = 0; j < 8; ++j) {
                int c = tx + 16 * j;
                float s = (c < 64) ? ns0 : ns1;
                p2[(size_t)row * 256 + cb * 128 + c] = acc[i][j] * s;
            }
        }
    }
}

// ---- 7) gather2: sequential relations, 4-edge unroll ------------------------
__global__ __launch_bounds__(256) void gather2_kernel(
    const float* __restrict__ p2,             // [N][256]
    const int2* __restrict__ csr_rec,
    const int* __restrict__ offs,
    const float* __restrict__ ndst,
    const float* __restrict__ b2,             // [4][64]
    float* __restrict__ out) {
    int wid = (blockIdx.x * 256 + threadIdx.x) >> 6;
    int lane = threadIdx.x & 63;
    if (wid >= N_NODES) return;
    int d = wid;
    float res = 0.0f;
#pragma unroll
    for (int r = 0; r < N_REL; ++r) {
        int e = offs[r * (N_NODES + 1) + d];
        int e1 = offs[r * (N_NODES + 1) + d + 1];
        const int2* rec = csr_rec + (size_t)r * N_EDGES;
        const float* col = p2 + r * 64 + lane;
        float a = 0.0f;
        for (; e + 3 < e1; e += 4) {
            int2 rc0 = rec[e], rc1 = rec[e + 1], rc2 = rec[e + 2], rc3 = rec[e + 3];
            float v0 = col[(size_t)rc0.x * 256];
            float v1 = col[(size_t)rc1.x * 256];
            float v2 = col[(size_t)rc2.x * 256];
            float v3 = col[(size_t)rc3.x * 256];
            a += (v0 + v1) + (v2 + v3);
        }
        for (; e < e1; ++e)
            a += col[(size_t)rec[e].x * 256];
        res += a * ndst[(size_t)r * N_NODES + d];
    }
    res = 0.25f * res + 0.25f * (b2[lane] + b2[64 + lane] + b2[128 + lane] + b2[192 + lane]);
    out[(size_t)d * OUTD + lane] = res;
}

// ----------------------------------------------------------------- launch ---
extern "C" void kernel_launch(void* const* d_in, const int* in_sizes, int n_in,
                              void* d_out, int out_size, void* d_ws, size_t ws_size,
                              hipStream_t stream) {
    const int* src = (const int*)d_in[1];
    const int* dst = (const int*)d_in[2];
    const float* emb = (const float*)d_in[3];
    const float* W1 = (const float*)d_in[4];
    const float* b1 = (const float*)d_in[5];
    const float* W2 = (const float*)d_in[6];
    const float* b2 = (const float*)d_in[7];
    float* out = (float*)d_out;

    char* p = (char*)d_ws;
    auto alloc = [&](size_t bytes) -> void* {
        void* q = (void*)p;
        p += (bytes + 255) & ~(size_t)255;
        return q;
    };
    unsigned* cnt_dst = (unsigned*)alloc((size_t)SLICES * N_REL * 2 * CHUNKW * 4); // 12.8 MB
    unsigned* cnt_src = (unsigned*)alloc((size_t)SLICES * N_REL * 2 * CHUNKW * 4); // 12.8 MB
    unsigned short* rank = (unsigned short*)alloc((size_t)N_REL * N_EDGES * 2);    // 4 MB
    int* offs = (int*)alloc((size_t)N_REL * (N_NODES + 1) * 4);
    int* bsum = (int*)alloc((size_t)N_REL * NBLK2 * 4);
    int2* csr_rec = (int2*)alloc((size_t)N_REL * N_EDGES * 8);                     // 16 MB
    float* nsrc = (float*)alloc((size_t)N_REL * N_NODES * 4);
    float* ndst = (float*)alloc((size_t)N_REL * N_NODES * 4);
    float* h1 = (float*)alloc((size_t)N_NODES * HID * 4);                          // 25.6 MB
    float* p2 = (float*)alloc((size_t)N_NODES * 256 * 4);                          // 51.2 MB
    size_t used = (size_t)(p - (char*)d_ws);
    size_t avail = ws_size > used ? ws_size - used : 0;
    size_t maxn = avail / (512 * 4);
    int npc = (int)(maxn > (size_t)N_NODES ? (size_t)N_NODES : maxn);
    if (npc < 256) npc = 256;
    float* agg = (float*)p;

    // CSR build: LDS histograms (no global atomics, no memset)
    hist_kernel<<<dim3(SLICES, 2, 8), 256, 0, stream>>>(src, dst, cnt_dst, cnt_src, rank);
    scan1_kernel<<<dim3(NBLK2, N_REL), 256, 0, stream>>>(cnt_dst, cnt_src, nsrc, ndst, offs, bsum);
    scan2_kernel<<<N_REL, 256, 0, stream>>>(bsum, offs);
    offs_fin_kernel<<<(N_REL * N_NODES + 255) / 256, 256, 0, stream>>>(bsum, offs);
    dim3 egrid((N_EDGES + 255) / 256, N_REL);
    place_kernel<<<egrid, 256, 0, stream>>>(src, dst, rank, cnt_dst, nsrc, offs, csr_rec);

    // layer 1: emb -> agg(chunked) -> h1
    for (int n0 = 0; n0 < N_NODES; n0 += npc) {
        int nn = (N_NODES - n0) < npc ? (N_NODES - n0) : npc;
        gather1_kernel<<<(nn + 3) / 4, 256, 0, stream>>>(emb, csr_rec, offs, ndst, agg, n0, nn);
        gemm1_kernel<<<(nn + 63) / 64, 256, 0, stream>>>(agg, W1, b1, h1, n0, nn);
    }
    // layer 2: h1 -> p2 (project-first, all relations) -> out
    dim3 g2grid((N_NODES + 63) / 64, 2);
    gemm2_kernel<<<g2grid, 256, 0, stream>>>(h1, W2, nsrc, p2);
    gather2_kernel<<<(N_NODES * 64 + 255) / 256, 256, 0, stream>>>(
        p2, csr_rec, offs, ndst, b2, out);
}

// Round 9
// 480.753 us; speedup vs baseline: 2.3722x; 1.1193x over previous
//
#include <hip/hip_runtime.h>
#include <hip/hip_bf16.h>

#define N_NODES 50000
#define N_REL   4
#define N_EDGES 500000
#define EMB     128
#define HID     128
#define OUTD    64
#define SLICES  32
#define EPS     (N_EDGES / SLICES)   // 15625 edges per slice (exact)
#define CHUNKN  25000                // nodes per chunk (2 chunks)
#define CHUNKW  12500                // packed u32 per chunk (2 x u16)
#define NBLK2   98                   // ceil(50000 / 512) scan1 blocks per rel

// ---- 1) hist: per-slice LDS histograms, NO global atomics ------------------
__global__ __launch_bounds__(256) void hist_kernel(
    const int* __restrict__ src, const int* __restrict__ dst,
    unsigned* __restrict__ cnt_dst, unsigned* __restrict__ cnt_src,
    unsigned short* __restrict__ rank) {
    const int s = blockIdx.x;
    const int ch = blockIdx.y;
    const int z = blockIdx.z;
    const int r = z & 3;
    const bool do_dst = (z < 4);
    const int t = threadIdx.x;
    __shared__ unsigned bins[CHUNKW];          // 50 KB: 25000 x u16 packed
    for (int i = t; i < CHUNKW; i += 256) bins[i] = 0;
    __syncthreads();
    const int* col = do_dst ? dst : src;
    const int c0 = ch * CHUNKN;
    for (int e = s * EPS + t; e < (s + 1) * EPS; e += 256) {
        int d = col[(size_t)r * N_EDGES + e];
        unsigned dl = (unsigned)(d - c0);
        if (dl < CHUNKN) {
            unsigned sh = (dl & 1) * 16;
            unsigned old = atomicAdd(&bins[dl >> 1], 1u << sh);
            if (do_dst)
                rank[(size_t)r * N_EDGES + e] = (unsigned short)((old >> sh) & 0xffffu);
        }
    }
    __syncthreads();
    unsigned* out = (do_dst ? cnt_dst : cnt_src)
                  + (((size_t)s * N_REL + r) * 2 + ch) * CHUNKW;
    for (int i = t; i < CHUNKW; i += 256) out[i] = bins[i];
}

// ---- 2a) scan1: slice-reduce + in-place slice-prefix + norms + block scan ---
__global__ __launch_bounds__(256) void scan1_kernel(
    unsigned* __restrict__ cnt_dst, const unsigned* __restrict__ cnt_src,
    float* __restrict__ nsrc, float* __restrict__ ndst,
    int* __restrict__ offs, int* __restrict__ bsum) {
    const int r = blockIdx.y;
    const int blk = blockIdx.x;
    const int t = threadIdx.x;
    const int pair = blk * 256 + t;            // 0 .. 24999
    int d0 = 0, d1 = 0;
    if (pair < CHUNKN) {
        int ch = (2 * pair) / CHUNKN;          // 0 or 1
        int i = pair - ch * CHUNKW;
        unsigned run0 = 0, run1 = 0;
#pragma unroll
        for (int s = 0; s < SLICES; ++s) {
            size_t idx = (((size_t)s * N_REL + r) * 2 + ch) * CHUNKW + i;
            unsigned v = cnt_dst[idx];
            cnt_dst[idx] = run0 | (run1 << 16); // exclusive slice-prefix (packed)
            run0 += v & 0xffffu;
            run1 += v >> 16;
        }
        d0 = (int)run0; d1 = (int)run1;
        unsigned s0 = 0, s1 = 0;
#pragma unroll
        for (int s = 0; s < SLICES; ++s) {
            unsigned v = cnt_src[(((size_t)s * N_REL + r) * 2 + ch) * CHUNKW + i];
            s0 += v & 0xffffu;
            s1 += v >> 16;
        }
        size_t nidx = (size_t)r * N_NODES + 2 * pair;
        nsrc[nidx]     = s0 ? rsqrtf((float)s0) : 0.0f;
        nsrc[nidx + 1] = s1 ? rsqrtf((float)s1) : 0.0f;
        ndst[nidx]     = d0 ? rsqrtf((float)d0) : 0.0f;
        ndst[nidx + 1] = d1 ? rsqrtf((float)d1) : 0.0f;
    }
    __shared__ int sh[256];
    int dsum = d0 + d1;
    sh[t] = dsum;
    __syncthreads();
#pragma unroll
    for (int off = 1; off < 256; off <<= 1) {
        int v = (t >= off) ? sh[t - off] : 0;
        __syncthreads();
        sh[t] += v;
        __syncthreads();
    }
    if (pair < CHUNKN) {
        int base = sh[t] - dsum;
        offs[r * (N_NODES + 1) + 2 * pair]     = base;
        offs[r * (N_NODES + 1) + 2 * pair + 1] = base + d0;
    }
    if (t == 255) bsum[r * NBLK2 + blk] = sh[255];
}

// ---- 2b) scan2 --------------------------------------------------------------
__global__ __launch_bounds__(256) void scan2_kernel(int* __restrict__ bsum,
                                                    int* __restrict__ offs) {
    const int r = blockIdx.x;
    const int t = threadIdx.x;
    __shared__ int sh[256];
    int v = (t < NBLK2) ? bsum[r * NBLK2 + t] : 0;
    sh[t] = v;
    __syncthreads();
#pragma unroll
    for (int off = 1; off < 256; off <<= 1) {
        int u = (t >= off) ? sh[t - off] : 0;
        __syncthreads();
        sh[t] += u;
        __syncthreads();
    }
    if (t < NBLK2) bsum[r * NBLK2 + t] = sh[t] - v;
    if (t == 0) offs[r * (N_NODES + 1) + N_NODES] = N_EDGES;
}

// ---- 2c) finalize offs ------------------------------------------------------
__global__ void offs_fin_kernel(const int* __restrict__ bsum, int* __restrict__ offs) {
    int i = blockIdx.x * blockDim.x + threadIdx.x;
    if (i >= N_REL * N_NODES) return;
    int r = i / N_NODES, n = i - r * N_NODES;
    offs[r * (N_NODES + 1) + n] += bsum[r * NBLK2 + (n >> 9)];
}

// ---- 3) place (no atomics) --------------------------------------------------
__global__ void place_kernel(const int* __restrict__ src, const int* __restrict__ dst,
                             const unsigned short* __restrict__ rank,
                             const unsigned* __restrict__ cnt_dst,
                             const float* __restrict__ nsrc,
                             const int* __restrict__ offs, int2* __restrict__ csr_rec) {
    int e = blockIdx.x * blockDim.x + threadIdx.x;
    int r = blockIdx.y;
    if (e >= N_EDGES) return;
    int s = e / EPS;
    int d = dst[(size_t)r * N_EDGES + e];
    int sg = src[(size_t)r * N_EDGES + e];
    int ch = d / CHUNKN;
    int dl = d - ch * CHUNKN;
    unsigned pv = cnt_dst[(((size_t)s * N_REL + r) * 2 + ch) * CHUNKW + (dl >> 1)];
    int base = (int)((pv >> ((dl & 1) * 16)) & 0xffffu);
    int p = offs[r * (N_NODES + 1) + d] + base + (int)rank[(size_t)r * N_EDGES + e];
    csr_rec[(size_t)r * N_EDGES + p] =
        make_int2(sg, __float_as_int(nsrc[(size_t)r * N_NODES + sg]));
}

// ---- 4) gather1 -------------------------------------------------------------
__global__ __launch_bounds__(256) void gather1_kernel(
    const float* __restrict__ x,
    const int2* __restrict__ csr_rec,
    const int* __restrict__ offs,
    const float* __restrict__ ndst,
    float* __restrict__ agg,
    int node0, int nnodes) {
    int wid = (blockIdx.x * 256 + threadIdx.x) >> 6;
    int lane = threadIdx.x & 63;
    if (wid >= nnodes) return;
    int d = node0 + wid;
    const float2* x2 = (const float2*)x;
    float2* arow = (float2*)(agg + (size_t)wid * (N_REL * EMB));
#pragma unroll
    for (int r = 0; r < N_REL; ++r) {
        int e = offs[r * (N_NODES + 1) + d];
        int e1 = offs[r * (N_NODES + 1) + d + 1];
        const int2* rec = csr_rec + (size_t)r * N_EDGES;
        float ax = 0.0f, ay = 0.0f;
        for (; e + 3 < e1; e += 4) {
            int2 rc0 = rec[e], rc1 = rec[e + 1], rc2 = rec[e + 2], rc3 = rec[e + 3];
            float2 v0 = x2[(size_t)rc0.x * 64 + lane];
            float2 v1 = x2[(size_t)rc1.x * 64 + lane];
            float2 v2 = x2[(size_t)rc2.x * 64 + lane];
            float2 v3 = x2[(size_t)rc3.x * 64 + lane];
            float w0 = __int_as_float(rc0.y), w1 = __int_as_float(rc1.y);
            float w2 = __int_as_float(rc2.y), w3 = __int_as_float(rc3.y);
            ax += v0.x * w0 + v1.x * w1 + v2.x * w2 + v3.x * w3;
            ay += v0.y * w0 + v1.y * w1 + v2.y * w2 + v3.y * w3;
        }
        for (; e < e1; ++e) {
            int2 rc = rec[e];
            float w = __int_as_float(rc.y);
            float2 v = x2[(size_t)rc.x * 64 + lane];
            ax += v.x * w;
            ay += v.y * w;
        }
        float sc = 0.25f * ndst[(size_t)r * N_NODES + d];
        float2 o; o.x = ax * sc; o.y = ay * sc;
        arow[r * 64 + lane] = o;
    }
}

// ---- 5) gemm1: h1 = agg[.][512] @ W1flat + bias; b128 inner loop ------------
// 64x128 tile, thread = 4 rows x 8 consecutive cols (tx*8..+7).
__global__ __launch_bounds__(256) void gemm1_kernel(
    const float* __restrict__ agg, const float* __restrict__ W,   // [512][128]
    const float* __restrict__ b1,
    float* __restrict__ h1, int node0, int nnodes) {
    constexpr int K = 512, HO = 128, KT = 32;
    __shared__ float xt[64][36];               // 36-pad: 16B aligned rows
    __shared__ float wt[KT][HO];
    const int t = threadIdx.x;
    const int tx = t & 15, ty = t >> 4;        // ty 0..15
    const int row0 = blockIdx.x * 64;
    float acc[4][8] = {};
    for (int k0 = 0; k0 < K; k0 += KT) {
#pragma unroll
        for (int q = 0; q < 2; ++q) {          // X tile: 512 float4
            int idx = t + q * 256;
            int row = idx >> 3, c4 = idx & 7;
            float4 v = {};
            if (row0 + row < nnodes)
                v = *(const float4*)&agg[(size_t)(row0 + row) * K + k0 + c4 * 4];
            *(float4*)&xt[row][c4 * 4] = v;
        }
#pragma unroll
        for (int q = 0; q < 4; ++q) {          // W tile: 1024 float4
            int idx = t + q * 256;
            int k = idx >> 5, c4 = idx & 31;
            *(float4*)&wt[k][c4 * 4] = *(const float4*)&W[(size_t)(k0 + k) * HO + c4 * 4];
        }
        __syncthreads();
#pragma unroll
        for (int kk = 0; kk < KT; kk += 4) {
            float xv[4][4];
#pragma unroll
            for (int i = 0; i < 4; ++i)
                *(float4*)&xv[i][0] = *(const float4*)&xt[ty + 16 * i][kk];
#pragma unroll
            for (int u = 0; u < 4; ++u) {
                float wv[8];
                *(float4*)&wv[0] = *(const float4*)&wt[kk + u][tx * 8];
                *(float4*)&wv[4] = *(const float4*)&wt[kk + u][tx * 8 + 4];
#pragma unroll
                for (int i = 0; i < 4; ++i)
#pragma unroll
                    for (int j = 0; j < 8; ++j) acc[i][j] += xv[i][u] * wv[j];
            }
        }
        __syncthreads();
    }
#pragma unroll
    for (int i = 0; i < 4; ++i) {
        int row = row0 + ty + 16 * i;
        if (row < nnodes) {
            float o[8];
#pragma unroll
            for (int j = 0; j < 8; ++j) {
                int c = tx * 8 + j;
                o[j] = acc[i][j] + 0.25f * (b1[c] + b1[HO + c] + b1[2 * HO + c] + b1[3 * HO + c]);
            }
            *(float4*)&h1[(size_t)(node0 + row) * HO + tx * 8]     = *(float4*)&o[0];
            *(float4*)&h1[(size_t)(node0 + row) * HO + tx * 8 + 4] = *(float4*)&o[4];
        }
    }
}

// ---- 6) gemm2: p2[n][cb*128 + c] = ns_{r(c)}[n] * (h1[n] @ W2cat)[c] --------
__global__ __launch_bounds__(256) void gemm2_kernel(
    const float* __restrict__ h1,             // [N][128]
    const float* __restrict__ W2,             // [4][128][64]
    const float* __restrict__ nsrc,           // [4][N]
    float* __restrict__ p2) {                 // [N][256]
    constexpr int K = 128, KT = 32;
    __shared__ float xt[64][36];
    __shared__ float wt[KT][128];
    const int t = threadIdx.x;
    const int tx = t & 15, ty = t >> 4;
    const int row0 = blockIdx.x * 64;
    const int cb = blockIdx.y;                 // 0 or 1
    float acc[4][8] = {};
    for (int k0 = 0; k0 < K; k0 += KT) {
#pragma unroll
        for (int q = 0; q < 2; ++q) {
            int idx = t + q * 256;
            int row = idx >> 3, c4 = idx & 7;
            float4 v = {};
            if (row0 + row < N_NODES)
                v = *(const float4*)&h1[(size_t)(row0 + row) * K + k0 + c4 * 4];
            *(float4*)&xt[row][c4 * 4] = v;
        }
#pragma unroll
        for (int q = 0; q < 4; ++q) {          // W tile: cols cb*128..+127
            int idx = t + q * 256;
            int k = idx >> 5, c4 = idx & 31;
            int r = cb * 2 + (c4 >> 4);
            int col = (c4 * 4) & 63;
            *(float4*)&wt[k][c4 * 4] =
                *(const float4*)&W2[((size_t)r * K + k0 + k) * 64 + col];
        }
        __syncthreads();
#pragma unroll
        for (int kk = 0; kk < KT; kk += 4) {
            float xv[4][4];
#pragma unroll
            for (int i = 0; i < 4; ++i)
                *(float4*)&xv[i][0] = *(const float4*)&xt[ty + 16 * i][kk];
#pragma unroll
            for (int u = 0; u < 4; ++u) {
                float wv[8];
                *(float4*)&wv[0] = *(const float4*)&wt[kk + u][tx * 8];
                *(float4*)&wv[4] = *(const float4*)&wt[kk + u][tx * 8 + 4];
#pragma unroll
                for (int i = 0; i < 4; ++i)
#pragma unroll
                    for (int j = 0; j < 8; ++j) acc[i][j] += xv[i][u] * wv[j];
            }
        }
        __syncthreads();
    }
    const int rr = cb * 2 + (tx >> 3);         // all 8 cols in one relation
#pragma unroll
    for (int i = 0; i < 4; ++i) {
        int row = row0 + ty + 16 * i;
        if (row < N_NODES) {
            float ns = nsrc[(size_t)rr * N_NODES + row];
            float o[8];
#pragma unroll
            for (int j = 0; j < 8; ++j) o[j] = acc[i][j] * ns;
            *(float4*)&p2[(size_t)row * 256 + cb * 128 + tx * 8]     = *(float4*)&o[0];
            *(float4*)&p2[(size_t)row * 256 + cb * 128 + tx * 8 + 4] = *(float4*)&o[4];
        }
    }
}

// ---- 7) gather2 -------------------------------------------------------------
__global__ __launch_bounds__(256) void gather2_kernel(
    const float* __restrict__ p2,
    const int2* __restrict__ csr_rec,
    const int* __restrict__ offs,
    const float* __restrict__ ndst,
    const float* __restrict__ b2,
    float* __restrict__ out) {
    int wid = (blockIdx.x * 256 + threadIdx.x) >> 6;
    int lane = threadIdx.x & 63;
    if (wid >= N_NODES) return;
    int d = wid;
    float res = 0.0f;
#pragma unroll
    for (int r = 0; r < N_REL; ++r) {
        int e = offs[r * (N_NODES + 1) + d];
        int e1 = offs[r * (N_NODES + 1) + d + 1];
        const int2* rec = csr_rec + (size_t)r * N_EDGES;
        const float* col = p2 + r * 64 + lane;
        float a = 0.0f;
        for (; e + 3 < e1; e += 4) {
            int2 rc0 = rec[e], rc1 = rec[e + 1], rc2 = rec[e + 2], rc3 = rec[e + 3];
            float v0 = col[(size_t)rc0.x * 256];
            float v1 = col[(size_t)rc1.x * 256];
            float v2 = col[(size_t)rc2.x * 256];
            float v3 = col[(size_t)rc3.x * 256];
            a += (v0 + v1) + (v2 + v3);
        }
        for (; e < e1; ++e)
            a += col[(size_t)rec[e].x * 256];
        res += a * ndst[(size_t)r * N_NODES + d];
    }
    res = 0.25f * res + 0.25f * (b2[lane] + b2[64 + lane] + b2[128 + lane] + b2[192 + lane]);
    out[(size_t)d * OUTD + lane] = res;
}

// ----------------------------------------------------------------- launch ---
extern "C" void kernel_launch(void* const* d_in, const int* in_sizes, int n_in,
                              void* d_out, int out_size, void* d_ws, size_t ws_size,
                              hipStream_t stream) {
    const int* src = (const int*)d_in[1];
    const int* dst = (const int*)d_in[2];
    const float* emb = (const float*)d_in[3];
    const float* W1 = (const float*)d_in[4];
    const float* b1 = (const float*)d_in[5];
    const float* W2 = (const float*)d_in[6];
    const float* b2 = (const float*)d_in[7];
    float* out = (float*)d_out;

    char* p = (char*)d_ws;
    auto alloc = [&](size_t bytes) -> void* {
        void* q = (void*)p;
        p += (bytes + 255) & ~(size_t)255;
        return q;
    };
    // ---- persistent (~44 MB)
    int* offs = (int*)alloc((size_t)N_REL * (N_NODES + 1) * 4);
    int* bsum = (int*)alloc((size_t)N_REL * NBLK2 * 4);
    float* nsrc = (float*)alloc((size_t)N_REL * N_NODES * 4);
    float* ndst = (float*)alloc((size_t)N_REL * N_NODES * 4);
    int2* csr_rec = (int2*)alloc((size_t)N_REL * N_EDGES * 8);               // 16 MB
    float* h1 = (float*)alloc((size_t)N_NODES * HID * 4);                    // 25.6 MB
    // ---- transient region X: CSR-build buffers, then agg, then p2 (aliased)
    char* X = p;
    size_t persistent = (size_t)(p - (char*)d_ws);
    unsigned* cnt_dst = (unsigned*)X;                                        // 12.8 MB
    unsigned* cnt_src = cnt_dst + (size_t)SLICES * N_REL * 2 * CHUNKW;       // 12.8 MB
    unsigned short* rank = (unsigned short*)(cnt_src + (size_t)SLICES * N_REL * 2 * CHUNKW); // 4 MB
    float* agg = (float*)X;            // reuses X after place_kernel is done
    float* p2  = (float*)X;            // reuses X after last gemm1 read of agg

    size_t avail = ws_size > persistent ? ws_size - persistent : 0;
    size_t maxn = avail / ((size_t)N_REL * EMB * 4);
    int npc = (int)(maxn > (size_t)N_NODES ? (size_t)N_NODES : maxn);
    if (npc < 256) npc = 256;

    // CSR build: LDS histograms (no global atomics, no memset)
    hist_kernel<<<dim3(SLICES, 2, 8), 256, 0, stream>>>(src, dst, cnt_dst, cnt_src, rank);
    scan1_kernel<<<dim3(NBLK2, N_REL), 256, 0, stream>>>(cnt_dst, cnt_src, nsrc, ndst, offs, bsum);
    scan2_kernel<<<N_REL, 256, 0, stream>>>(bsum, offs);
    offs_fin_kernel<<<(N_REL * N_NODES + 255) / 256, 256, 0, stream>>>(bsum, offs);
    dim3 egrid((N_EDGES + 255) / 256, N_REL);
    place_kernel<<<egrid, 256, 0, stream>>>(src, dst, rank, cnt_dst, nsrc, offs, csr_rec);

    // layer 1: emb -> agg -> h1 (single chunk when workspace permits)
    for (int n0 = 0; n0 < N_NODES; n0 += npc) {
        int nn = (N_NODES - n0) < npc ? (N_NODES - n0) : npc;
        gather1_kernel<<<(nn + 3) / 4, 256, 0, stream>>>(emb, csr_rec, offs, ndst, agg, n0, nn);
        gemm1_kernel<<<(nn + 63) / 64, 256, 0, stream>>>(agg, W1, b1, h1, n0, nn);
    }
    // layer 2: h1 -> p2 (project-first) -> out
    dim3 g2grid((N_NODES + 63) / 64, 2);
    gemm2_kernel<<<g2grid, 256, 0, stream>>>(h1, W2, nsrc, p2);
    gather2_kernel<<<(N_NODES * 64 + 255) / 256, 256, 0, stream>>>(
        p2, csr_rec, offs, ndst, b2, out);
}

// Round 10
// 462.871 us; speedup vs baseline: 2.4638x; 1.0386x over previous
//
#include <hip/hip_runtime.h>
#include <hip/hip_bf16.h>

#define N_NODES 50000
#define N_REL   4
#define N_EDGES 500000
#define EMB     128
#define HID     128
#define OUTD    64
#define SLICES  32
#define EPS     (N_EDGES / SLICES)   // 15625 edges per slice (exact)
#define CHUNKN  25000                // nodes per chunk (2 chunks)
#define CHUNKW  12500                // packed u32 per chunk (2 x u16)
#define NBLK2   98                   // ceil(50000 / 512) scan1 blocks per rel

__device__ __forceinline__ unsigned short f2bf(float f) {   // RNE bf16 pack
    unsigned u = __float_as_uint(f);
    u = (u + 0x7fffu + ((u >> 16) & 1u)) >> 16;
    return (unsigned short)u;
}
__device__ __forceinline__ float bf2f(unsigned short v) {
    return __uint_as_float(((unsigned)v) << 16);
}

// ---- 1) hist: per-slice LDS histograms, NO global atomics ------------------
__global__ __launch_bounds__(256) void hist_kernel(
    const int* __restrict__ src, const int* __restrict__ dst,
    unsigned* __restrict__ cnt_dst, unsigned* __restrict__ cnt_src,
    unsigned short* __restrict__ rank) {
    const int s = blockIdx.x;
    const int ch = blockIdx.y;
    const int z = blockIdx.z;
    const int r = z & 3;
    const bool do_dst = (z < 4);
    const int t = threadIdx.x;
    __shared__ unsigned bins[CHUNKW];          // 50 KB: 25000 x u16 packed
    for (int i = t; i < CHUNKW; i += 256) bins[i] = 0;
    __syncthreads();
    const int* col = do_dst ? dst : src;
    const int c0 = ch * CHUNKN;
    for (int e = s * EPS + t; e < (s + 1) * EPS; e += 256) {
        int d = col[(size_t)r * N_EDGES + e];
        unsigned dl = (unsigned)(d - c0);
        if (dl < CHUNKN) {
            unsigned sh = (dl & 1) * 16;
            unsigned old = atomicAdd(&bins[dl >> 1], 1u << sh);
            if (do_dst)
                rank[(size_t)r * N_EDGES + e] = (unsigned short)((old >> sh) & 0xffffu);
        }
    }
    __syncthreads();
    unsigned* out = (do_dst ? cnt_dst : cnt_src)
                  + (((size_t)s * N_REL + r) * 2 + ch) * CHUNKW;
    for (int i = t; i < CHUNKW; i += 256) out[i] = bins[i];
}

// ---- 2a) scan1 --------------------------------------------------------------
__global__ __launch_bounds__(256) void scan1_kernel(
    unsigned* __restrict__ cnt_dst, const unsigned* __restrict__ cnt_src,
    float* __restrict__ nsrc, float* __restrict__ ndst,
    int* __restrict__ offs, int* __restrict__ bsum) {
    const int r = blockIdx.y;
    const int blk = blockIdx.x;
    const int t = threadIdx.x;
    const int pair = blk * 256 + t;            // 0 .. 24999
    int d0 = 0, d1 = 0;
    if (pair < CHUNKN) {
        int ch = (2 * pair) / CHUNKN;          // 0 or 1
        int i = pair - ch * CHUNKW;
        unsigned run0 = 0, run1 = 0;
#pragma unroll
        for (int s = 0; s < SLICES; ++s) {
            size_t idx = (((size_t)s * N_REL + r) * 2 + ch) * CHUNKW + i;
            unsigned v = cnt_dst[idx];
            cnt_dst[idx] = run0 | (run1 << 16); // exclusive slice-prefix (packed)
            run0 += v & 0xffffu;
            run1 += v >> 16;
        }
        d0 = (int)run0; d1 = (int)run1;
        unsigned s0 = 0, s1 = 0;
#pragma unroll
        for (int s = 0; s < SLICES; ++s) {
            unsigned v = cnt_src[(((size_t)s * N_REL + r) * 2 + ch) * CHUNKW + i];
            s0 += v & 0xffffu;
            s1 += v >> 16;
        }
        size_t nidx = (size_t)r * N_NODES + 2 * pair;
        nsrc[nidx]     = s0 ? rsqrtf((float)s0) : 0.0f;
        nsrc[nidx + 1] = s1 ? rsqrtf((float)s1) : 0.0f;
        ndst[nidx]     = d0 ? rsqrtf((float)d0) : 0.0f;
        ndst[nidx + 1] = d1 ? rsqrtf((float)d1) : 0.0f;
    }
    __shared__ int sh[256];
    int dsum = d0 + d1;
    sh[t] = dsum;
    __syncthreads();
#pragma unroll
    for (int off = 1; off < 256; off <<= 1) {
        int v = (t >= off) ? sh[t - off] : 0;
        __syncthreads();
        sh[t] += v;
        __syncthreads();
    }
    if (pair < CHUNKN) {
        int base = sh[t] - dsum;
        offs[r * (N_NODES + 1) + 2 * pair]     = base;
        offs[r * (N_NODES + 1) + 2 * pair + 1] = base + d0;
    }
    if (t == 255) bsum[r * NBLK2 + blk] = sh[255];
}

// ---- 2b) scan2 --------------------------------------------------------------
__global__ __launch_bounds__(256) void scan2_kernel(int* __restrict__ bsum,
                                                    int* __restrict__ offs) {
    const int r = blockIdx.x;
    const int t = threadIdx.x;
    __shared__ int sh[256];
    int v = (t < NBLK2) ? bsum[r * NBLK2 + t] : 0;
    sh[t] = v;
    __syncthreads();
#pragma unroll
    for (int off = 1; off < 256; off <<= 1) {
        int u = (t >= off) ? sh[t - off] : 0;
        __syncthreads();
        sh[t] += u;
        __syncthreads();
    }
    if (t < NBLK2) bsum[r * NBLK2 + t] = sh[t] - v;
    if (t == 0) offs[r * (N_NODES + 1) + N_NODES] = N_EDGES;
}

// ---- 2c) finalize offs ------------------------------------------------------
__global__ void offs_fin_kernel(const int* __restrict__ bsum, int* __restrict__ offs) {
    int i = blockIdx.x * blockDim.x + threadIdx.x;
    if (i >= N_REL * N_NODES) return;
    int r = i / N_NODES, n = i - r * N_NODES;
    offs[r * (N_NODES + 1) + n] += bsum[r * NBLK2 + (n >> 9)];
}

// ---- 3) place (no atomics) --------------------------------------------------
__global__ void place_kernel(const int* __restrict__ src, const int* __restrict__ dst,
                             const unsigned short* __restrict__ rank,
                             const unsigned* __restrict__ cnt_dst,
                             const float* __restrict__ nsrc,
                             const int* __restrict__ offs, int2* __restrict__ csr_rec) {
    int e = blockIdx.x * blockDim.x + threadIdx.x;
    int r = blockIdx.y;
    if (e >= N_EDGES) return;
    int s = e / EPS;
    int d = dst[(size_t)r * N_EDGES + e];
    int sg = src[(size_t)r * N_EDGES + e];
    int ch = d / CHUNKN;
    int dl = d - ch * CHUNKN;
    unsigned pv = cnt_dst[(((size_t)s * N_REL + r) * 2 + ch) * CHUNKW + (dl >> 1)];
    int base = (int)((pv >> ((dl & 1) * 16)) & 0xffffu);
    int p = offs[r * (N_NODES + 1) + d] + base + (int)rank[(size_t)r * N_EDGES + e];
    csr_rec[(size_t)r * N_EDGES + p] =
        make_int2(sg, __float_as_int(nsrc[(size_t)r * N_NODES + sg]));
}

// ---- 4) gather1: one wave per dst node, 8-deep edge ILP ---------------------
__global__ __launch_bounds__(256) void gather1_kernel(
    const float* __restrict__ x,
    const int2* __restrict__ csr_rec,
    const int* __restrict__ offs,
    const float* __restrict__ ndst,
    float* __restrict__ agg,
    int node0, int nnodes) {
    int wid = (blockIdx.x * 256 + threadIdx.x) >> 6;
    int lane = threadIdx.x & 63;
    if (wid >= nnodes) return;
    int d = node0 + wid;
    const float2* x2 = (const float2*)x;
    float2* arow = (float2*)(agg + (size_t)wid * (N_REL * EMB));
    for (int r = 0; r < N_REL; ++r) {
        int e = offs[r * (N_NODES + 1) + d];
        int e1 = offs[r * (N_NODES + 1) + d + 1];
        const int2* rec = csr_rec + (size_t)r * N_EDGES;
        float ax = 0.0f, ay = 0.0f;
        for (; e + 7 < e1; e += 8) {
            int2 rc[8];
#pragma unroll
            for (int u = 0; u < 8; ++u) rc[u] = rec[e + u];
            float2 v[8];
#pragma unroll
            for (int u = 0; u < 8; ++u) v[u] = x2[(size_t)rc[u].x * 64 + lane];
#pragma unroll
            for (int u = 0; u < 8; ++u) {
                float w = __int_as_float(rc[u].y);
                ax += v[u].x * w;
                ay += v[u].y * w;
            }
        }
        for (; e + 3 < e1; e += 4) {
            int2 rc[4];
#pragma unroll
            for (int u = 0; u < 4; ++u) rc[u] = rec[e + u];
            float2 v[4];
#pragma unroll
            for (int u = 0; u < 4; ++u) v[u] = x2[(size_t)rc[u].x * 64 + lane];
#pragma unroll
            for (int u = 0; u < 4; ++u) {
                float w = __int_as_float(rc[u].y);
                ax += v[u].x * w;
                ay += v[u].y * w;
            }
        }
        for (; e < e1; ++e) {
            int2 rc = rec[e];
            float w = __int_as_float(rc.y);
            float2 v = x2[(size_t)rc.x * 64 + lane];
            ax += v.x * w;
            ay += v.y * w;
        }
        float sc = 0.25f * ndst[(size_t)r * N_NODES + d];
        float2 o; o.x = ax * sc; o.y = ay * sc;
        arow[r * 64 + lane] = o;
    }
}

// ---- 5) gemm1: h1 = agg[.][512] @ W1flat + bias; b128 inner loop ------------
__global__ __launch_bounds__(256) void gemm1_kernel(
    const float* __restrict__ agg, const float* __restrict__ W,   // [512][128]
    const float* __restrict__ b1,
    float* __restrict__ h1, int node0, int nnodes) {
    constexpr int K = 512, HO = 128, KT = 32;
    __shared__ float xt[64][36];               // 36-pad: 16B aligned rows
    __shared__ float wt[KT][HO];
    const int t = threadIdx.x;
    const int tx = t & 15, ty = t >> 4;        // ty 0..15
    const int row0 = blockIdx.x * 64;
    float acc[4][8] = {};
    for (int k0 = 0; k0 < K; k0 += KT) {
#pragma unroll
        for (int q = 0; q < 2; ++q) {          // X tile: 512 float4
            int idx = t + q * 256;
            int row = idx >> 3, c4 = idx & 7;
            float4 v = {};
            if (row0 + row < nnodes)
                v = *(const float4*)&agg[(size_t)(row0 + row) * K + k0 + c4 * 4];
            *(float4*)&xt[row][c4 * 4] = v;
        }
#pragma unroll
        for (int q = 0; q < 4; ++q) {          // W tile: 1024 float4
            int idx = t + q * 256;
            int k = idx >> 5, c4 = idx & 31;
            *(float4*)&wt[k][c4 * 4] = *(const float4*)&W[(size_t)(k0 + k) * HO + c4 * 4];
        }
        __syncthreads();
#pragma unroll
        for (int kk = 0; kk < KT; kk += 4) {
            float xv[4][4];
#pragma unroll
            for (int i = 0; i < 4; ++i)
                *(float4*)&xv[i][0] = *(const float4*)&xt[ty + 16 * i][kk];
#pragma unroll
            for (int u = 0; u < 4; ++u) {
                float wv[8];
                *(float4*)&wv[0] = *(const float4*)&wt[kk + u][tx * 8];
                *(float4*)&wv[4] = *(const float4*)&wt[kk + u][tx * 8 + 4];
#pragma unroll
                for (int i = 0; i < 4; ++i)
#pragma unroll
                    for (int j = 0; j < 8; ++j) acc[i][j] += xv[i][u] * wv[j];
            }
        }
        __syncthreads();
    }
#pragma unroll
    for (int i = 0; i < 4; ++i) {
        int row = row0 + ty + 16 * i;
        if (row < nnodes) {
            float o[8];
#pragma unroll
            for (int j = 0; j < 8; ++j) {
                int c = tx * 8 + j;
                o[j] = acc[i][j] + 0.25f * (b1[c] + b1[HO + c] + b1[2 * HO + c] + b1[3 * HO + c]);
            }
            *(float4*)&h1[(size_t)(node0 + row) * HO + tx * 8]     = *(float4*)&o[0];
            *(float4*)&h1[(size_t)(node0 + row) * HO + tx * 8 + 4] = *(float4*)&o[4];
        }
    }
}

// ---- 6) gemm2: p2b[n][cb*128 + c] = bf16( ns_{r(c)}[n] * (h1[n] @ W2cat)[c] )
__global__ __launch_bounds__(256) void gemm2_kernel(
    const float* __restrict__ h1,             // [N][128]
    const float* __restrict__ W2,             // [4][128][64]
    const float* __restrict__ nsrc,           // [4][N]
    unsigned short* __restrict__ p2b) {       // [N][256] bf16
    constexpr int K = 128, KT = 32;
    __shared__ float xt[64][36];
    __shared__ float wt[KT][128];
    const int t = threadIdx.x;
    const int tx = t & 15, ty = t >> 4;
    const int row0 = blockIdx.x * 64;
    const int cb = blockIdx.y;                 // 0 or 1
    float acc[4][8] = {};
    for (int k0 = 0; k0 < K; k0 += KT) {
#pragma unroll
        for (int q = 0; q < 2; ++q) {
            int idx = t + q * 256;
            int row = idx >> 3, c4 = idx & 7;
            float4 v = {};
            if (row0 + row < N_NODES)
                v = *(const float4*)&h1[(size_t)(row0 + row) * K + k0 + c4 * 4];
            *(float4*)&xt[row][c4 * 4] = v;
        }
#pragma unroll
        for (int q = 0; q < 4; ++q) {          // W tile: cols cb*128..+127
            int idx = t + q * 256;
            int k = idx >> 5, c4 = idx & 31;
            int r = cb * 2 + (c4 >> 4);
            int col = (c4 * 4) & 63;
            *(float4*)&wt[k][c4 * 4] =
                *(const float4*)&W2[((size_t)r * K + k0 + k) * 64 + col];
        }
        __syncthreads();
#pragma unroll
        for (int kk = 0; kk < KT; kk += 4) {
            float xv[4][4];
#pragma unroll
            for (int i = 0; i < 4; ++i)
                *(float4*)&xv[i][0] = *(const float4*)&xt[ty + 16 * i][kk];
#pragma unroll
            for (int u = 0; u < 4; ++u) {
                float wv[8];
                *(float4*)&wv[0] = *(const float4*)&wt[kk + u][tx * 8];
                *(float4*)&wv[4] = *(const float4*)&wt[kk + u][tx * 8 + 4];
#pragma unroll
                for (int i = 0; i < 4; ++i)
#pragma unroll
                    for (int j = 0; j < 8; ++j) acc[i][j] += xv[i][u] * wv[j];
            }
        }
        __syncthreads();
    }
    const int rr = cb * 2 + (tx >> 3);         // all 8 cols in one relation
#pragma unroll
    for (int i = 0; i < 4; ++i) {
        int row = row0 + ty + 16 * i;
        if (row < N_NODES) {
            float ns = nsrc[(size_t)rr * N_NODES + row];
            unsigned short o[8];
#pragma unroll
            for (int j = 0; j < 8; ++j) o[j] = f2bf(acc[i][j] * ns);
            *(ushort4*)&p2b[(size_t)row * 256 + cb * 128 + tx * 8]     = *(ushort4*)&o[0];
            *(ushort4*)&p2b[(size_t)row * 256 + cb * 128 + tx * 8 + 4] = *(ushort4*)&o[4];
        }
    }
}

// ---- 7) gather2: bf16 reads, 8-deep edge ILP --------------------------------
__global__ __launch_bounds__(256) void gather2_kernel(
    const unsigned short* __restrict__ p2b,   // [N][256] bf16
    const int2* __restrict__ csr_rec,
    const int* __restrict__ offs,
    const float* __restrict__ ndst,
    const float* __restrict__ b2,
    float* __restrict__ out) {
    int wid = (blockIdx.x * 256 + threadIdx.x) >> 6;
    int lane = threadIdx.x & 63;
    if (wid >= N_NODES) return;
    int d = wid;
    float res = 0.0f;
    for (int r = 0; r < N_REL; ++r) {
        int e = offs[r * (N_NODES + 1) + d];
        int e1 = offs[r * (N_NODES + 1) + d + 1];
        const int2* rec = csr_rec + (size_t)r * N_EDGES;
        const unsigned short* col = p2b + r * 64 + lane;
        float a = 0.0f;
        for (; e + 7 < e1; e += 8) {
            int sidx[8];
#pragma unroll
            for (int u = 0; u < 8; ++u) sidx[u] = rec[e + u].x;
            unsigned short v[8];
#pragma unroll
            for (int u = 0; u < 8; ++u) v[u] = col[(size_t)sidx[u] * 256];
#pragma unroll
            for (int u = 0; u < 8; ++u) a += bf2f(v[u]);
        }
        for (; e + 3 < e1; e += 4) {
            int sidx[4];
#pragma unroll
            for (int u = 0; u < 4; ++u) sidx[u] = rec[e + u].x;
            unsigned short v[4];
#pragma unroll
            for (int u = 0; u < 4; ++u) v[u] = col[(size_t)sidx[u] * 256];
#pragma unroll
            for (int u = 0; u < 4; ++u) a += bf2f(v[u]);
        }
        for (; e < e1; ++e)
            a += bf2f(col[(size_t)rec[e].x * 256]);
        res += a * ndst[(size_t)r * N_NODES + d];
    }
    res = 0.25f * res + 0.25f * (b2[lane] + b2[64 + lane] + b2[128 + lane] + b2[192 + lane]);
    out[(size_t)d * OUTD + lane] = res;
}

// ----------------------------------------------------------------- launch ---
extern "C" void kernel_launch(void* const* d_in, const int* in_sizes, int n_in,
                              void* d_out, int out_size, void* d_ws, size_t ws_size,
                              hipStream_t stream) {
    const int* src = (const int*)d_in[1];
    const int* dst = (const int*)d_in[2];
    const float* emb = (const float*)d_in[3];
    const float* W1 = (const float*)d_in[4];
    const float* b1 = (const float*)d_in[5];
    const float* W2 = (const float*)d_in[6];
    const float* b2 = (const float*)d_in[7];
    float* out = (float*)d_out;

    char* p = (char*)d_ws;
    auto alloc = [&](size_t bytes) -> void* {
        void* q = (void*)p;
        p += (bytes + 255) & ~(size_t)255;
        return q;
    };
    // ---- persistent (~44 MB)
    int* offs = (int*)alloc((size_t)N_REL * (N_NODES + 1) * 4);
    int* bsum = (int*)alloc((size_t)N_REL * NBLK2 * 4);
    float* nsrc = (float*)alloc((size_t)N_REL * N_NODES * 4);
    float* ndst = (float*)alloc((size_t)N_REL * N_NODES * 4);
    int2* csr_rec = (int2*)alloc((size_t)N_REL * N_EDGES * 8);               // 16 MB
    float* h1 = (float*)alloc((size_t)N_NODES * HID * 4);                    // 25.6 MB
    // ---- transient region X: CSR-build buffers, then agg, then p2b (aliased)
    char* X = p;
    size_t persistent = (size_t)(p - (char*)d_ws);
    unsigned* cnt_dst = (unsigned*)X;                                        // 12.8 MB
    unsigned* cnt_src = cnt_dst + (size_t)SLICES * N_REL * 2 * CHUNKW;       // 12.8 MB
    unsigned short* rank = (unsigned short*)(cnt_src + (size_t)SLICES * N_REL * 2 * CHUNKW); // 4 MB
    float* agg = (float*)X;            // reuses X after place_kernel is done
    unsigned short* p2b = (unsigned short*)X;  // reuses X after last gemm1 read

    size_t avail = ws_size > persistent ? ws_size - persistent : 0;
    size_t maxn = avail / ((size_t)N_REL * EMB * 4);
    int npc = (int)(maxn > (size_t)N_NODES ? (size_t)N_NODES : maxn);
    if (npc < 256) npc = 256;

    // CSR build: LDS histograms (no global atomics, no memset)
    hist_kernel<<<dim3(SLICES, 2, 8), 256, 0, stream>>>(src, dst, cnt_dst, cnt_src, rank);
    scan1_kernel<<<dim3(NBLK2, N_REL), 256, 0, stream>>>(cnt_dst, cnt_src, nsrc, ndst, offs, bsum);
    scan2_kernel<<<N_REL, 256, 0, stream>>>(bsum, offs);
    offs_fin_kernel<<<(N_REL * N_NODES + 255) / 256, 256, 0, stream>>>(bsum, offs);
    dim3 egrid((N_EDGES + 255) / 256, N_REL);
    place_kernel<<<egrid, 256, 0, stream>>>(src, dst, rank, cnt_dst, nsrc, offs, csr_rec);

    // layer 1: emb -> agg -> h1 (single chunk when workspace permits)
    for (int n0 = 0; n0 < N_NODES; n0 += npc) {
        int nn = (N_NODES - n0) < npc ? (N_NODES - n0) : npc;
        gather1_kernel<<<(nn + 3) / 4, 256, 0, stream>>>(emb, csr_rec, offs, ndst, agg, n0, nn);
        gemm1_kernel<<<(nn + 63) / 64, 256, 0, stream>>>(agg, W1, b1, h1, n0, nn);
    }
    // layer 2: h1 -> p2b (project-first, bf16) -> out
    dim3 g2grid((N_NODES + 63) / 64, 2);
    gemm2_kernel<<<g2grid, 256, 0, stream>>>(h1, W2, nsrc, p2b);
    gather2_kernel<<<(N_NODES * 64 + 255) / 256, 256, 0, stream>>>(
        p2b, csr_rec, offs, ndst, b2, out);
}

// Round 11
// 408.950 us; speedup vs baseline: 2.7887x; 1.1319x over previous
//
#include <hip/hip_runtime.h>
#include <hip/hip_bf16.h>

#define N_NODES 50000
#define N_REL   4
#define N_EDGES 500000
#define EMB     128
#define HID     128
#define OUTD    64
#define SLICES  32
#define EPS     (N_EDGES / SLICES)   // 15625 edges per slice (exact)
#define CHUNKN  25000                // nodes per chunk (2 chunks)
#define CHUNKW  12500                // packed u32 per chunk (2 x u16)
#define NBLK2   98                   // ceil(50000 / 512) scan1 blocks per rel

__device__ __forceinline__ unsigned short f2bf(float f) {   // RNE bf16 pack
    unsigned u = __float_as_uint(f);
    u = (u + 0x7fffu + ((u >> 16) & 1u)) >> 16;
    return (unsigned short)u;
}
__device__ __forceinline__ float bf2f(unsigned short v) {
    return __uint_as_float(((unsigned)v) << 16);
}

// ---- 0) cvt: emb fp32 -> bf16 table ----------------------------------------
__global__ void cvt_kernel(const float* __restrict__ in, unsigned short* __restrict__ outb) {
    int i = blockIdx.x * blockDim.x + threadIdx.x;
    if (i >= N_NODES * EMB / 4) return;
    float4 v = *(const float4*)&in[(size_t)i * 4];
    ushort4 o;
    o.x = f2bf(v.x); o.y = f2bf(v.y); o.z = f2bf(v.z); o.w = f2bf(v.w);
    *(ushort4*)&outb[(size_t)i * 4] = o;
}

// ---- 1) hist: per-slice LDS histograms, NO global atomics ------------------
__global__ __launch_bounds__(256) void hist_kernel(
    const int* __restrict__ src, const int* __restrict__ dst,
    unsigned* __restrict__ cnt_dst, unsigned* __restrict__ cnt_src,
    unsigned short* __restrict__ rank) {
    const int s = blockIdx.x;
    const int ch = blockIdx.y;
    const int z = blockIdx.z;
    const int r = z & 3;
    const bool do_dst = (z < 4);
    const int t = threadIdx.x;
    __shared__ unsigned bins[CHUNKW];          // 50 KB: 25000 x u16 packed
    for (int i = t; i < CHUNKW; i += 256) bins[i] = 0;
    __syncthreads();
    const int* col = do_dst ? dst : src;
    const int c0 = ch * CHUNKN;
    for (int e = s * EPS + t; e < (s + 1) * EPS; e += 256) {
        int d = col[(size_t)r * N_EDGES + e];
        unsigned dl = (unsigned)(d - c0);
        if (dl < CHUNKN) {
            unsigned sh = (dl & 1) * 16;
            unsigned old = atomicAdd(&bins[dl >> 1], 1u << sh);
            if (do_dst)
                rank[(size_t)r * N_EDGES + e] = (unsigned short)((old >> sh) & 0xffffu);
        }
    }
    __syncthreads();
    unsigned* out = (do_dst ? cnt_dst : cnt_src)
                  + (((size_t)s * N_REL + r) * 2 + ch) * CHUNKW;
    for (int i = t; i < CHUNKW; i += 256) out[i] = bins[i];
}

// ---- 2a) scan1 --------------------------------------------------------------
__global__ __launch_bounds__(256) void scan1_kernel(
    unsigned* __restrict__ cnt_dst, const unsigned* __restrict__ cnt_src,
    float* __restrict__ nsrc, float* __restrict__ ndst,
    int* __restrict__ offs, int* __restrict__ bsum) {
    const int r = blockIdx.y;
    const int blk = blockIdx.x;
    const int t = threadIdx.x;
    const int pair = blk * 256 + t;            // 0 .. 24999
    int d0 = 0, d1 = 0;
    if (pair < CHUNKN) {
        int ch = (2 * pair) / CHUNKN;          // 0 or 1
        int i = pair - ch * CHUNKW;
        unsigned run0 = 0, run1 = 0;
#pragma unroll
        for (int s = 0; s < SLICES; ++s) {
            size_t idx = (((size_t)s * N_REL + r) * 2 + ch) * CHUNKW + i;
            unsigned v = cnt_dst[idx];
            cnt_dst[idx] = run0 | (run1 << 16); // exclusive slice-prefix (packed)
            run0 += v & 0xffffu;
            run1 += v >> 16;
        }
        d0 = (int)run0; d1 = (int)run1;
        unsigned s0 = 0, s1 = 0;
#pragma unroll
        for (int s = 0; s < SLICES; ++s) {
            unsigned v = cnt_src[(((size_t)s * N_REL + r) * 2 + ch) * CHUNKW + i];
            s0 += v & 0xffffu;
            s1 += v >> 16;
        }
        size_t nidx = (size_t)r * N_NODES + 2 * pair;
        nsrc[nidx]     = s0 ? rsqrtf((float)s0) : 0.0f;
        nsrc[nidx + 1] = s1 ? rsqrtf((float)s1) : 0.0f;
        ndst[nidx]     = d0 ? rsqrtf((float)d0) : 0.0f;
        ndst[nidx + 1] = d1 ? rsqrtf((float)d1) : 0.0f;
    }
    __shared__ int sh[256];
    int dsum = d0 + d1;
    sh[t] = dsum;
    __syncthreads();
#pragma unroll
    for (int off = 1; off < 256; off <<= 1) {
        int v = (t >= off) ? sh[t - off] : 0;
        __syncthreads();
        sh[t] += v;
        __syncthreads();
    }
    if (pair < CHUNKN) {
        int base = sh[t] - dsum;
        offs[r * (N_NODES + 1) + 2 * pair]     = base;
        offs[r * (N_NODES + 1) + 2 * pair + 1] = base + d0;
    }
    if (t == 255) bsum[r * NBLK2 + blk] = sh[255];
}

// ---- 2b) scan2 --------------------------------------------------------------
__global__ __launch_bounds__(256) void scan2_kernel(int* __restrict__ bsum,
                                                    int* __restrict__ offs) {
    const int r = blockIdx.x;
    const int t = threadIdx.x;
    __shared__ int sh[256];
    int v = (t < NBLK2) ? bsum[r * NBLK2 + t] : 0;
    sh[t] = v;
    __syncthreads();
#pragma unroll
    for (int off = 1; off < 256; off <<= 1) {
        int u = (t >= off) ? sh[t - off] : 0;
        __syncthreads();
        sh[t] += u;
        __syncthreads();
    }
    if (t < NBLK2) bsum[r * NBLK2 + t] = sh[t] - v;
    if (t == 0) offs[r * (N_NODES + 1) + N_NODES] = N_EDGES;
}

// ---- 2c) finalize offs ------------------------------------------------------
__global__ void offs_fin_kernel(const int* __restrict__ bsum, int* __restrict__ offs) {
    int i = blockIdx.x * blockDim.x + threadIdx.x;
    if (i >= N_REL * N_NODES) return;
    int r = i / N_NODES, n = i - r * N_NODES;
    offs[r * (N_NODES + 1) + n] += bsum[r * NBLK2 + (n >> 9)];
}

// ---- 3) place (no atomics) --------------------------------------------------
__global__ void place_kernel(const int* __restrict__ src, const int* __restrict__ dst,
                             const unsigned short* __restrict__ rank,
                             const unsigned* __restrict__ cnt_dst,
                             const float* __restrict__ nsrc,
                             const int* __restrict__ offs, int2* __restrict__ csr_rec) {
    int e = blockIdx.x * blockDim.x + threadIdx.x;
    int r = blockIdx.y;
    if (e >= N_EDGES) return;
    int s = e / EPS;
    int d = dst[(size_t)r * N_EDGES + e];
    int sg = src[(size_t)r * N_EDGES + e];
    int ch = d / CHUNKN;
    int dl = d - ch * CHUNKN;
    unsigned pv = cnt_dst[(((size_t)s * N_REL + r) * 2 + ch) * CHUNKW + (dl >> 1)];
    int base = (int)((pv >> ((dl & 1) * 16)) & 0xffffu);
    int p = offs[r * (N_NODES + 1) + d] + base + (int)rank[(size_t)r * N_EDGES + e];
    csr_rec[(size_t)r * N_EDGES + p] =
        make_int2(sg, __float_as_int(nsrc[(size_t)r * N_NODES + sg]));
}

// ---- 4) gather1: bf16 table reads, bf16 agg writes, 8-deep ILP --------------
__global__ __launch_bounds__(256) void gather1_kernel(
    const unsigned short* __restrict__ xb,    // [N][128] bf16
    const int2* __restrict__ csr_rec,
    const int* __restrict__ offs,
    const float* __restrict__ ndst,
    unsigned* __restrict__ aggb,              // [N][256] u32 (= 512 bf16)
    int node0, int nnodes) {
    int wid = (blockIdx.x * 256 + threadIdx.x) >> 6;
    int lane = threadIdx.x & 63;
    if (wid >= nnodes) return;
    int d = node0 + wid;
    const unsigned* x1 = (const unsigned*)xb;  // row = 64 u32 (2 bf16 each)
    unsigned* arow = aggb + (size_t)wid * (N_REL * 64);
    for (int r = 0; r < N_REL; ++r) {
        int e = offs[r * (N_NODES + 1) + d];
        int e1 = offs[r * (N_NODES + 1) + d + 1];
        const int2* rec = csr_rec + (size_t)r * N_EDGES;
        float ax = 0.0f, ay = 0.0f;
        for (; e + 7 < e1; e += 8) {
            int2 rc[8];
#pragma unroll
            for (int u = 0; u < 8; ++u) rc[u] = rec[e + u];
            unsigned v[8];
#pragma unroll
            for (int u = 0; u < 8; ++u) v[u] = x1[(size_t)rc[u].x * 64 + lane];
#pragma unroll
            for (int u = 0; u < 8; ++u) {
                float w = __int_as_float(rc[u].y);
                ax += __uint_as_float(v[u] << 16) * w;
                ay += __uint_as_float(v[u] & 0xffff0000u) * w;
            }
        }
        for (; e + 3 < e1; e += 4) {
            int2 rc[4];
#pragma unroll
            for (int u = 0; u < 4; ++u) rc[u] = rec[e + u];
            unsigned v[4];
#pragma unroll
            for (int u = 0; u < 4; ++u) v[u] = x1[(size_t)rc[u].x * 64 + lane];
#pragma unroll
            for (int u = 0; u < 4; ++u) {
                float w = __int_as_float(rc[u].y);
                ax += __uint_as_float(v[u] << 16) * w;
                ay += __uint_as_float(v[u] & 0xffff0000u) * w;
            }
        }
        for (; e < e1; ++e) {
            int2 rc = rec[e];
            float w = __int_as_float(rc.y);
            unsigned v = x1[(size_t)rc.x * 64 + lane];
            ax += __uint_as_float(v << 16) * w;
            ay += __uint_as_float(v & 0xffff0000u) * w;
        }
        float sc = 0.25f * ndst[(size_t)r * N_NODES + d];
        arow[r * 64 + lane] = (unsigned)f2bf(ax * sc) | ((unsigned)f2bf(ay * sc) << 16);
    }
}

// ---- 5) gemm1: h1 = aggb(bf16)[.][512] @ W1flat + bias ----------------------
__global__ __launch_bounds__(256) void gemm1_kernel(
    const unsigned short* __restrict__ aggb,  // [N][512] bf16
    const float* __restrict__ W,              // [512][128]
    const float* __restrict__ b1,
    float* __restrict__ h1, int node0, int nnodes) {
    constexpr int K = 512, HO = 128, KT = 32;
    __shared__ float xt[64][36];               // 144 B rows: 16B-aligned
    __shared__ float wt[KT][HO];
    const int t = threadIdx.x;
    const int tx = t & 15, ty = t >> 4;
    const int row0 = blockIdx.x * 64;
    float acc[4][8] = {};
    for (int k0 = 0; k0 < K; k0 += KT) {
#pragma unroll
        for (int q = 0; q < 2; ++q) {          // X tile: 64x32 bf16 = 512 uint2
            int idx = t + q * 256;
            int row = idx >> 3, c2 = idx & 7;  // uint2 = 4 bf16
            uint2 v = make_uint2(0u, 0u);
            if (row0 + row < nnodes)
                v = *(const uint2*)&aggb[(size_t)(row0 + row) * K + k0 + c2 * 4];
            float4 f;
            f.x = __uint_as_float(v.x << 16);
            f.y = __uint_as_float(v.x & 0xffff0000u);
            f.z = __uint_as_float(v.y << 16);
            f.w = __uint_as_float(v.y & 0xffff0000u);
            *(float4*)&xt[row][c2 * 4] = f;
        }
#pragma unroll
        for (int q = 0; q < 4; ++q) {          // W tile: 1024 float4
            int idx = t + q * 256;
            int k = idx >> 5, c4 = idx & 31;
            *(float4*)&wt[k][c4 * 4] = *(const float4*)&W[(size_t)(k0 + k) * HO + c4 * 4];
        }
        __syncthreads();
#pragma unroll
        for (int kk = 0; kk < KT; kk += 4) {
            float xv[4][4];
#pragma unroll
            for (int i = 0; i < 4; ++i)
                *(float4*)&xv[i][0] = *(const float4*)&xt[ty + 16 * i][kk];
#pragma unroll
            for (int u = 0; u < 4; ++u) {
                float wv[8];
                *(float4*)&wv[0] = *(const float4*)&wt[kk + u][tx * 8];
                *(float4*)&wv[4] = *(const float4*)&wt[kk + u][tx * 8 + 4];
#pragma unroll
                for (int i = 0; i < 4; ++i)
#pragma unroll
                    for (int j = 0; j < 8; ++j) acc[i][j] += xv[i][u] * wv[j];
            }
        }
        __syncthreads();
    }
#pragma unroll
    for (int i = 0; i < 4; ++i) {
        int row = row0 + ty + 16 * i;
        if (row < nnodes) {
            float o[8];
#pragma unroll
            for (int j = 0; j < 8; ++j) {
                int c = tx * 8 + j;
                o[j] = acc[i][j] + 0.25f * (b1[c] + b1[HO + c] + b1[2 * HO + c] + b1[3 * HO + c]);
            }
            *(float4*)&h1[(size_t)(node0 + row) * HO + tx * 8]     = *(float4*)&o[0];
            *(float4*)&h1[(size_t)(node0 + row) * HO + tx * 8 + 4] = *(float4*)&o[4];
        }
    }
}

// ---- 6) gemm2: p2b[n][cb*128 + c] = bf16( ns_{r(c)}[n] * (h1[n] @ W2cat)[c] )
__global__ __launch_bounds__(256) void gemm2_kernel(
    const float* __restrict__ h1,             // [N][128]
    const float* __restrict__ W2,             // [4][128][64]
    const float* __restrict__ nsrc,           // [4][N]
    unsigned short* __restrict__ p2b) {       // [N][256] bf16
    constexpr int K = 128, KT = 32;
    __shared__ float xt[64][36];
    __shared__ float wt[KT][128];
    const int t = threadIdx.x;
    const int tx = t & 15, ty = t >> 4;
    const int row0 = blockIdx.x * 64;
    const int cb = blockIdx.y;                 // 0 or 1
    float acc[4][8] = {};
    for (int k0 = 0; k0 < K; k0 += KT) {
#pragma unroll
        for (int q = 0; q < 2; ++q) {
            int idx = t + q * 256;
            int row = idx >> 3, c4 = idx & 7;
            float4 v = {};
            if (row0 + row < N_NODES)
                v = *(const float4*)&h1[(size_t)(row0 + row) * K + k0 + c4 * 4];
            *(float4*)&xt[row][c4 * 4] = v;
        }
#pragma unroll
        for (int q = 0; q < 4; ++q) {          // W tile: cols cb*128..+127
            int idx = t + q * 256;
            int k = idx >> 5, c4 = idx & 31;
            int r = cb * 2 + (c4 >> 4);
            int col = (c4 * 4) & 63;
            *(float4*)&wt[k][c4 * 4] =
                *(const float4*)&W2[((size_t)r * K + k0 + k) * 64 + col];
        }
        __syncthreads();
#pragma unroll
        for (int kk = 0; kk < KT; kk += 4) {
            float xv[4][4];
#pragma unroll
            for (int i = 0; i < 4; ++i)
                *(float4*)&xv[i][0] = *(const float4*)&xt[ty + 16 * i][kk];
#pragma unroll
            for (int u = 0; u < 4; ++u) {
                float wv[8];
                *(float4*)&wv[0] = *(const float4*)&wt[kk + u][tx * 8];
                *(float4*)&wv[4] = *(const float4*)&wt[kk + u][tx * 8 + 4];
#pragma unroll
                for (int i = 0; i < 4; ++i)
#pragma unroll
                    for (int j = 0; j < 8; ++j) acc[i][j] += xv[i][u] * wv[j];
            }
        }
        __syncthreads();
    }
    const int rr = cb * 2 + (tx >> 3);         // all 8 cols in one relation
#pragma unroll
    for (int i = 0; i < 4; ++i) {
        int row = row0 + ty + 16 * i;
        if (row < N_NODES) {
            float ns = nsrc[(size_t)rr * N_NODES + row];
            unsigned short o[8];
#pragma unroll
            for (int j = 0; j < 8; ++j) o[j] = f2bf(acc[i][j] * ns);
            *(ushort4*)&p2b[(size_t)row * 256 + cb * 128 + tx * 8]     = *(ushort4*)&o[0];
            *(ushort4*)&p2b[(size_t)row * 256 + cb * 128 + tx * 8 + 4] = *(ushort4*)&o[4];
        }
    }
}

// ---- 7) gather2: bf16 reads, 8-deep edge ILP --------------------------------
__global__ __launch_bounds__(256) void gather2_kernel(
    const unsigned short* __restrict__ p2b,   // [N][256] bf16
    const int2* __restrict__ csr_rec,
    const int* __restrict__ offs,
    const float* __restrict__ ndst,
    const float* __restrict__ b2,
    float* __restrict__ out) {
    int wid = (blockIdx.x * 256 + threadIdx.x) >> 6;
    int lane = threadIdx.x & 63;
    if (wid >= N_NODES) return;
    int d = wid;
    float res = 0.0f;
    for (int r = 0; r < N_REL; ++r) {
        int e = offs[r * (N_NODES + 1) + d];
        int e1 = offs[r * (N_NODES + 1) + d + 1];
        const int2* rec = csr_rec + (size_t)r * N_EDGES;
        const unsigned short* col = p2b + r * 64 + lane;
        float a = 0.0f;
        for (; e + 7 < e1; e += 8) {
            int sidx[8];
#pragma unroll
            for (int u = 0; u < 8; ++u) sidx[u] = rec[e + u].x;
            unsigned short v[8];
#pragma unroll
            for (int u = 0; u < 8; ++u) v[u] = col[(size_t)sidx[u] * 256];
#pragma unroll
            for (int u = 0; u < 8; ++u) a += bf2f(v[u]);
        }
        for (; e + 3 < e1; e += 4) {
            int sidx[4];
#pragma unroll
            for (int u = 0; u < 4; ++u) sidx[u] = rec[e + u].x;
            unsigned short v[4];
#pragma unroll
            for (int u = 0; u < 4; ++u) v[u] = col[(size_t)sidx[u] * 256];
#pragma unroll
            for (int u = 0; u < 4; ++u) a += bf2f(v[u]);
        }
        for (; e < e1; ++e)
            a += bf2f(col[(size_t)rec[e].x * 256]);
        res += a * ndst[(size_t)r * N_NODES + d];
    }
    res = 0.25f * res + 0.25f * (b2[lane] + b2[64 + lane] + b2[128 + lane] + b2[192 + lane]);
    out[(size_t)d * OUTD + lane] = res;
}

// ----------------------------------------------------------------- launch ---
extern "C" void kernel_launch(void* const* d_in, const int* in_sizes, int n_in,
                              void* d_out, int out_size, void* d_ws, size_t ws_size,
                              hipStream_t stream) {
    const int* src = (const int*)d_in[1];
    const int* dst = (const int*)d_in[2];
    const float* emb = (const float*)d_in[3];
    const float* W1 = (const float*)d_in[4];
    const float* b1 = (const float*)d_in[5];
    const float* W2 = (const float*)d_in[6];
    const float* b2 = (const float*)d_in[7];
    float* out = (float*)d_out;

    char* p = (char*)d_ws;
    auto alloc = [&](size_t bytes) -> void* {
        void* q = (void*)p;
        p += (bytes + 255) & ~(size_t)255;
        return q;
    };
    // ---- persistent (~57 MB)
    int* offs = (int*)alloc((size_t)N_REL * (N_NODES + 1) * 4);
    int* bsum = (int*)alloc((size_t)N_REL * NBLK2 * 4);
    float* nsrc = (float*)alloc((size_t)N_REL * N_NODES * 4);
    float* ndst = (float*)alloc((size_t)N_REL * N_NODES * 4);
    int2* csr_rec = (int2*)alloc((size_t)N_REL * N_EDGES * 8);               // 16 MB
    float* h1 = (float*)alloc((size_t)N_NODES * HID * 4);                    // 25.6 MB
    unsigned short* embb = (unsigned short*)alloc((size_t)N_NODES * EMB * 2); // 12.8 MB
    // ---- transient region X: CSR-build buffers, then aggb, then p2b (aliased)
    char* X = p;
    size_t persistent = (size_t)(p - (char*)d_ws);
    unsigned* cnt_dst = (unsigned*)X;                                        // 12.8 MB
    unsigned* cnt_src = cnt_dst + (size_t)SLICES * N_REL * 2 * CHUNKW;       // 12.8 MB
    unsigned short* rank = (unsigned short*)(cnt_src + (size_t)SLICES * N_REL * 2 * CHUNKW); // 4 MB
    unsigned* aggb = (unsigned*)X;              // [N][256] u32, 51.2 MB, after place
    unsigned short* p2b = (unsigned short*)X;   // [N][256] bf16, 25.6 MB, after gemm1

    size_t avail = ws_size > persistent ? ws_size - persistent : 0;
    size_t maxn = avail / ((size_t)N_REL * EMB * 2);
    int npc = (int)(maxn > (size_t)N_NODES ? (size_t)N_NODES : maxn);
    if (npc < 256) npc = 256;

    // emb -> bf16 table (independent of CSR build)
    cvt_kernel<<<(N_NODES * EMB / 4 + 255) / 256, 256, 0, stream>>>(emb, embb);

    // CSR build: LDS histograms (no global atomics, no memset)
    hist_kernel<<<dim3(SLICES, 2, 8), 256, 0, stream>>>(src, dst, cnt_dst, cnt_src, rank);
    scan1_kernel<<<dim3(NBLK2, N_REL), 256, 0, stream>>>(cnt_dst, cnt_src, nsrc, ndst, offs, bsum);
    scan2_kernel<<<N_REL, 256, 0, stream>>>(bsum, offs);
    offs_fin_kernel<<<(N_REL * N_NODES + 255) / 256, 256, 0, stream>>>(bsum, offs);
    dim3 egrid((N_EDGES + 255) / 256, N_REL);
    place_kernel<<<egrid, 256, 0, stream>>>(src, dst, rank, cnt_dst, nsrc, offs, csr_rec);

    // layer 1: embb -> aggb (bf16) -> h1
    for (int n0 = 0; n0 < N_NODES; n0 += npc) {
        int nn = (N_NODES - n0) < npc ? (N_NODES - n0) : npc;
        gather1_kernel<<<(nn + 3) / 4, 256, 0, stream>>>(embb, csr_rec, offs, ndst, aggb, n0, nn);
        gemm1_kernel<<<(nn + 63) / 64, 256, 0, stream>>>(
            (const unsigned short*)aggb, W1, b1, h1, n0, nn);
    }
    // layer 2: h1 -> p2b (project-first, bf16) -> out
    dim3 g2grid((N_NODES + 63) / 64, 2);
    gemm2_kernel<<<g2grid, 256, 0, stream>>>(h1, W2, nsrc, p2b);
    gather2_kernel<<<(N_NODES * 64 + 255) / 256, 256, 0, stream>>>(
        p2b, csr_rec, offs, ndst, b2, out);
}

// Round 12
// 325.367 us; speedup vs baseline: 3.5051x; 1.2569x over previous
//
#include <hip/hip_runtime.h>
#include <hip/hip_bf16.h>

#define N_NODES 50000
#define N_REL   4
#define N_EDGES 500000
#define EMB     128
#define HID     128
#define OUTD    64
#define SLICES  32
#define EPS     (N_EDGES / SLICES)   // 15625 edges per slice (exact)
#define CHUNKN  25000                // nodes per chunk (2 chunks)
#define CHUNKW  12500                // packed u32 per chunk (2 x u16)
#define NBLK2   98                   // ceil(50000 / 512) scan1 blocks per rel

typedef __attribute__((ext_vector_type(8))) short short8v;   // 8 bf16 = 4 VGPR
typedef __attribute__((ext_vector_type(4))) float float4v;   // mfma acc

__device__ __forceinline__ unsigned short f2bf(float f) {   // RNE bf16 pack
    unsigned u = __float_as_uint(f);
    u = (u + 0x7fffu + ((u >> 16) & 1u)) >> 16;
    return (unsigned short)u;
}
__device__ __forceinline__ float bf2f(unsigned short v) {
    return __uint_as_float(((unsigned)v) << 16);
}

// ---- 0a) cvt: emb fp32 -> bf16 table ---------------------------------------
__global__ void cvt_kernel(const float* __restrict__ in, unsigned short* __restrict__ outb) {
    int i = blockIdx.x * blockDim.x + threadIdx.x;
    if (i >= N_NODES * EMB / 4) return;
    float4 v = *(const float4*)&in[(size_t)i * 4];
    ushort4 o;
    o.x = f2bf(v.x); o.y = f2bf(v.y); o.z = f2bf(v.z); o.w = f2bf(v.w);
    *(ushort4*)&outb[(size_t)i * 4] = o;
}

// ---- 0b) pack W1 [512][128] f32 -> mfma B-fragment order, bf16 -------------
// frag idx = (ks*8 + ct)*64 + lane; elem j: B[k=ks*32+(l>>4)*8+j][n=ct*16+(l&15)]
__global__ void packW1_kernel(const float* __restrict__ W1, unsigned short* __restrict__ W1p) {
    int idx = blockIdx.x * blockDim.x + threadIdx.x;
    if (idx >= 16 * 8 * 64) return;
    int l = idx & 63, ct = (idx >> 6) & 7, ks = idx >> 9;
    int n = ct * 16 + (l & 15);
    int k0 = ks * 32 + (l >> 4) * 8;
    ushort4 o0, o1;
    o0.x = f2bf(W1[(size_t)(k0 + 0) * 128 + n]);
    o0.y = f2bf(W1[(size_t)(k0 + 1) * 128 + n]);
    o0.z = f2bf(W1[(size_t)(k0 + 2) * 128 + n]);
    o0.w = f2bf(W1[(size_t)(k0 + 3) * 128 + n]);
    o1.x = f2bf(W1[(size_t)(k0 + 4) * 128 + n]);
    o1.y = f2bf(W1[(size_t)(k0 + 5) * 128 + n]);
    o1.z = f2bf(W1[(size_t)(k0 + 6) * 128 + n]);
    o1.w = f2bf(W1[(size_t)(k0 + 7) * 128 + n]);
    *(ushort4*)&W1p[(size_t)idx * 8]     = o0;
    *(ushort4*)&W1p[(size_t)idx * 8 + 4] = o1;
}

// ---- 0c) pack W2 [4][128][64] -> B-fragments for cols 0..255 ----------------
__global__ void packW2_kernel(const float* __restrict__ W2, unsigned short* __restrict__ W2p) {
    int idx = blockIdx.x * blockDim.x + threadIdx.x;
    if (idx >= 4 * 16 * 64) return;
    int l = idx & 63, ct = (idx >> 6) & 15, ks = idx >> 10;
    int n = ct * 16 + (l & 15);
    int r = n >> 6, cc = n & 63;
    int k0 = ks * 32 + (l >> 4) * 8;
    ushort4 o0, o1;
    o0.x = f2bf(W2[((size_t)r * 128 + k0 + 0) * 64 + cc]);
    o0.y = f2bf(W2[((size_t)r * 128 + k0 + 1) * 64 + cc]);
    o0.z = f2bf(W2[((size_t)r * 128 + k0 + 2) * 64 + cc]);
    o0.w = f2bf(W2[((size_t)r * 128 + k0 + 3) * 64 + cc]);
    o1.x = f2bf(W2[((size_t)r * 128 + k0 + 4) * 64 + cc]);
    o1.y = f2bf(W2[((size_t)r * 128 + k0 + 5) * 64 + cc]);
    o1.z = f2bf(W2[((size_t)r * 128 + k0 + 6) * 64 + cc]);
    o1.w = f2bf(W2[((size_t)r * 128 + k0 + 7) * 64 + cc]);
    *(ushort4*)&W2p[(size_t)idx * 8]     = o0;
    *(ushort4*)&W2p[(size_t)idx * 8 + 4] = o1;
}

// ---- 1) hist: per-slice LDS histograms, NO global atomics ------------------
__global__ __launch_bounds__(256) void hist_kernel(
    const int* __restrict__ src, const int* __restrict__ dst,
    unsigned* __restrict__ cnt_dst, unsigned* __restrict__ cnt_src,
    unsigned short* __restrict__ rank) {
    const int s = blockIdx.x;
    const int ch = blockIdx.y;
    const int z = blockIdx.z;
    const int r = z & 3;
    const bool do_dst = (z < 4);
    const int t = threadIdx.x;
    __shared__ unsigned bins[CHUNKW];          // 50 KB: 25000 x u16 packed
    for (int i = t; i < CHUNKW; i += 256) bins[i] = 0;
    __syncthreads();
    const int* col = do_dst ? dst : src;
    const int c0 = ch * CHUNKN;
    for (int e = s * EPS + t; e < (s + 1) * EPS; e += 256) {
        int d = col[(size_t)r * N_EDGES + e];
        unsigned dl = (unsigned)(d - c0);
        if (dl < CHUNKN) {
            unsigned sh = (dl & 1) * 16;
            unsigned old = atomicAdd(&bins[dl >> 1], 1u << sh);
            if (do_dst)
                rank[(size_t)r * N_EDGES + e] = (unsigned short)((old >> sh) & 0xffffu);
        }
    }
    __syncthreads();
    unsigned* out = (do_dst ? cnt_dst : cnt_src)
                  + (((size_t)s * N_REL + r) * 2 + ch) * CHUNKW;
    for (int i = t; i < CHUNKW; i += 256) out[i] = bins[i];
}

// ---- 2a) scan1 --------------------------------------------------------------
__global__ __launch_bounds__(256) void scan1_kernel(
    unsigned* __restrict__ cnt_dst, const unsigned* __restrict__ cnt_src,
    float* __restrict__ nsrc, float* __restrict__ ndst,
    int* __restrict__ offs, int* __restrict__ bsum) {
    const int r = blockIdx.y;
    const int blk = blockIdx.x;
    const int t = threadIdx.x;
    const int pair = blk * 256 + t;            // 0 .. 24999
    int d0 = 0, d1 = 0;
    if (pair < CHUNKN) {
        int ch = (2 * pair) / CHUNKN;          // 0 or 1
        int i = pair - ch * CHUNKW;
        unsigned run0 = 0, run1 = 0;
#pragma unroll
        for (int s = 0; s < SLICES; ++s) {
            size_t idx = (((size_t)s * N_REL + r) * 2 + ch) * CHUNKW + i;
            unsigned v = cnt_dst[idx];
            cnt_dst[idx] = run0 | (run1 << 16); // exclusive slice-prefix (packed)
            run0 += v & 0xffffu;
            run1 += v >> 16;
        }
        d0 = (int)run0; d1 = (int)run1;
        unsigned s0 = 0, s1 = 0;
#pragma unroll
        for (int s = 0; s < SLICES; ++s) {
            unsigned v = cnt_src[(((size_t)s * N_REL + r) * 2 + ch) * CHUNKW + i];
            s0 += v & 0xffffu;
            s1 += v >> 16;
        }
        size_t nidx = (size_t)r * N_NODES + 2 * pair;
        nsrc[nidx]     = s0 ? rsqrtf((float)s0) : 0.0f;
        nsrc[nidx + 1] = s1 ? rsqrtf((float)s1) : 0.0f;
        ndst[nidx]     = d0 ? rsqrtf((float)d0) : 0.0f;
        ndst[nidx + 1] = d1 ? rsqrtf((float)d1) : 0.0f;
    }
    __shared__ int sh[256];
    int dsum = d0 + d1;
    sh[t] = dsum;
    __syncthreads();
#pragma unroll
    for (int off = 1; off < 256; off <<= 1) {
        int v = (t >= off) ? sh[t - off] : 0;
        __syncthreads();
        sh[t] += v;
        __syncthreads();
    }
    if (pair < CHUNKN) {
        int base = sh[t] - dsum;
        offs[r * (N_NODES + 1) + 2 * pair]     = base;
        offs[r * (N_NODES + 1) + 2 * pair + 1] = base + d0;
    }
    if (t == 255) bsum[r * NBLK2 + blk] = sh[255];
}

// ---- 2b) scan2 --------------------------------------------------------------
__global__ __launch_bounds__(256) void scan2_kernel(int* __restrict__ bsum,
                                                    int* __restrict__ offs) {
    const int r = blockIdx.x;
    const int t = threadIdx.x;
    __shared__ int sh[256];
    int v = (t < NBLK2) ? bsum[r * NBLK2 + t] : 0;
    sh[t] = v;
    __syncthreads();
#pragma unroll
    for (int off = 1; off < 256; off <<= 1) {
        int u = (t >= off) ? sh[t - off] : 0;
        __syncthreads();
        sh[t] += u;
        __syncthreads();
    }
    if (t < NBLK2) bsum[r * NBLK2 + t] = sh[t] - v;
    if (t == 0) offs[r * (N_NODES + 1) + N_NODES] = N_EDGES;
}

// ---- 2c) finalize offs ------------------------------------------------------
__global__ void offs_fin_kernel(const int* __restrict__ bsum, int* __restrict__ offs) {
    int i = blockIdx.x * blockDim.x + threadIdx.x;
    if (i >= N_REL * N_NODES) return;
    int r = i / N_NODES, n = i - r * N_NODES;
    offs[r * (N_NODES + 1) + n] += bsum[r * NBLK2 + (n >> 9)];
}

// ---- 3) place (no atomics) --------------------------------------------------
__global__ void place_kernel(const int* __restrict__ src, const int* __restrict__ dst,
                             const unsigned short* __restrict__ rank,
                             const unsigned* __restrict__ cnt_dst,
                             const float* __restrict__ nsrc,
                             const int* __restrict__ offs, int2* __restrict__ csr_rec) {
    int e = blockIdx.x * blockDim.x + threadIdx.x;
    int r = blockIdx.y;
    if (e >= N_EDGES) return;
    int s = e / EPS;
    int d = dst[(size_t)r * N_EDGES + e];
    int sg = src[(size_t)r * N_EDGES + e];
    int ch = d / CHUNKN;
    int dl = d - ch * CHUNKN;
    unsigned pv = cnt_dst[(((size_t)s * N_REL + r) * 2 + ch) * CHUNKW + (dl >> 1)];
    int base = (int)((pv >> ((dl & 1) * 16)) & 0xffffu);
    int p = offs[r * (N_NODES + 1) + d] + base + (int)rank[(size_t)r * N_EDGES + e];
    csr_rec[(size_t)r * N_EDGES + p] =
        make_int2(sg, __float_as_int(nsrc[(size_t)r * N_NODES + sg]));
}

// ---- 4) gather1: bf16 table reads, bf16 agg writes, 8-deep ILP --------------
__global__ __launch_bounds__(256) void gather1_kernel(
    const unsigned short* __restrict__ xb,    // [N][128] bf16
    const int2* __restrict__ csr_rec,
    const int* __restrict__ offs,
    const float* __restrict__ ndst,
    unsigned* __restrict__ aggb,              // [N][256] u32 (= 512 bf16)
    int node0, int nnodes) {
    int wid = (blockIdx.x * 256 + threadIdx.x) >> 6;
    int lane = threadIdx.x & 63;
    if (wid >= nnodes) return;
    int d = node0 + wid;
    const unsigned* x1 = (const unsigned*)xb;  // row = 64 u32 (2 bf16 each)
    unsigned* arow = aggb + (size_t)wid * (N_REL * 64);
    for (int r = 0; r < N_REL; ++r) {
        int e = offs[r * (N_NODES + 1) + d];
        int e1 = offs[r * (N_NODES + 1) + d + 1];
        const int2* rec = csr_rec + (size_t)r * N_EDGES;
        float ax = 0.0f, ay = 0.0f;
        for (; e + 7 < e1; e += 8) {
            int2 rc[8];
#pragma unroll
            for (int u = 0; u < 8; ++u) rc[u] = rec[e + u];
            unsigned v[8];
#pragma unroll
            for (int u = 0; u < 8; ++u) v[u] = x1[(size_t)rc[u].x * 64 + lane];
#pragma unroll
            for (int u = 0; u < 8; ++u) {
                float w = __int_as_float(rc[u].y);
                ax += __uint_as_float(v[u] << 16) * w;
                ay += __uint_as_float(v[u] & 0xffff0000u) * w;
            }
        }
        for (; e + 3 < e1; e += 4) {
            int2 rc[4];
#pragma unroll
            for (int u = 0; u < 4; ++u) rc[u] = rec[e + u];
            unsigned v[4];
#pragma unroll
            for (int u = 0; u < 4; ++u) v[u] = x1[(size_t)rc[u].x * 64 + lane];
#pragma unroll
            for (int u = 0; u < 4; ++u) {
                float w = __int_as_float(rc[u].y);
                ax += __uint_as_float(v[u] << 16) * w;
                ay += __uint_as_float(v[u] & 0xffff0000u) * w;
            }
        }
        for (; e < e1; ++e) {
            int2 rc = rec[e];
            float w = __int_as_float(rc.y);
            unsigned v = x1[(size_t)rc.x * 64 + lane];
            ax += __uint_as_float(v << 16) * w;
            ay += __uint_as_float(v & 0xffff0000u) * w;
        }
        float sc = 0.25f * ndst[(size_t)r * N_NODES + d];
        arow[r * 64 + lane] = (unsigned)f2bf(ax * sc) | ((unsigned)f2bf(ay * sc) << 16);
    }
}

// ---- 5) gemm1 MFMA: h1b = aggb[.][512](bf16) @ W1p + bias -> bf16 -----------
// 4 waves/block; wave w: rows blk*64 + w*16, all 128 cols (8 tiles). No LDS.
__global__ __launch_bounds__(256) void gemm1_mfma(
    const unsigned short* __restrict__ aggb,  // [N][512] bf16
    const unsigned short* __restrict__ W1p,   // packed fragments
    const float* __restrict__ b1,
    unsigned short* __restrict__ h1b,         // [N][128] bf16
    int nnodes) {
    const int t = threadIdx.x;
    const int w = t >> 6, l = t & 63;
    const int row_base = blockIdx.x * 64 + w * 16;
    const int m = l & 15, kg = l >> 4;
    float4v acc[8];
#pragma unroll
    for (int ct = 0; ct < 8; ++ct) acc[ct] = (float4v){0.f, 0.f, 0.f, 0.f};
    const int arow = row_base + m;
    const bool aok = (arow < nnodes);
    const short8v* ap = (const short8v*)(aggb + (size_t)arow * 512 + kg * 8);
    const short8v* bp = (const short8v*)W1p;
#pragma unroll
    for (int ks = 0; ks < 16; ++ks) {
        short8v a = (short8v){0,0,0,0,0,0,0,0};
        if (aok) a = ap[ks * 4];               // +32 bf16 per ks
#pragma unroll
        for (int ct = 0; ct < 8; ++ct) {
            short8v b = bp[(ks * 8 + ct) * 64 + l];
            acc[ct] = __builtin_amdgcn_mfma_f32_16x16x32_bf16(a, b, acc[ct], 0, 0, 0);
        }
    }
    const int orow0 = row_base + kg * 4;
#pragma unroll
    for (int ct = 0; ct < 8; ++ct) {
        int c = ct * 16 + m;
        float bias = 0.25f * (b1[c] + b1[128 + c] + b1[256 + c] + b1[384 + c]);
#pragma unroll
        for (int i = 0; i < 4; ++i) {
            int row = orow0 + i;
            if (row < nnodes)
                h1b[(size_t)row * 128 + c] = f2bf(acc[ct][i] + bias);
        }
    }
}

// ---- 6) gemm2 MFMA: p2b = rowscale(h1b[.][128] @ W2p) -> bf16 ---------------
// wave w: rows blk*64 + w*16, 256 cols (16 tiles). No LDS.
__global__ __launch_bounds__(256) void gemm2_mfma(
    const unsigned short* __restrict__ h1b,   // [N][128] bf16
    const unsigned short* __restrict__ W2p,   // packed fragments
    const float* __restrict__ nsrc,           // [4][N]
    unsigned short* __restrict__ p2b) {       // [N][256] bf16
    const int t = threadIdx.x;
    const int w = t >> 6, l = t & 63;
    const int row_base = blockIdx.x * 64 + w * 16;
    const int m = l & 15, kg = l >> 4;
    float4v acc[16];
#pragma unroll
    for (int ct = 0; ct < 16; ++ct) acc[ct] = (float4v){0.f, 0.f, 0.f, 0.f};
    const int arow = row_base + m;
    const bool aok = (arow < N_NODES);
    const short8v* ap = (const short8v*)(h1b + (size_t)arow * 128 + kg * 8);
    const short8v* bp = (const short8v*)W2p;
#pragma unroll
    for (int ks = 0; ks < 4; ++ks) {
        short8v a = (short8v){0,0,0,0,0,0,0,0};
        if (aok) a = ap[ks * 4];
#pragma unroll
        for (int ct = 0; ct < 16; ++ct) {
            short8v b = bp[(ks * 16 + ct) * 64 + l];
            acc[ct] = __builtin_amdgcn_mfma_f32_16x16x32_bf16(a, b, acc[ct], 0, 0, 0);
        }
    }
    const int orow0 = row_base + kg * 4;
#pragma unroll
    for (int ct = 0; ct < 16; ++ct) {
        int c = ct * 16 + m;
        int r = c >> 6;
#pragma unroll
        for (int i = 0; i < 4; ++i) {
            int row = orow0 + i;
            if (row < N_NODES)
                p2b[(size_t)row * 256 + c] = f2bf(acc[ct][i] * nsrc[(size_t)r * N_NODES + row]);
        }
    }
}

// ---- 7) gather2: bf16 reads, 8-deep edge ILP --------------------------------
__global__ __launch_bounds__(256) void gather2_kernel(
    const unsigned short* __restrict__ p2b,   // [N][256] bf16
    const int2* __restrict__ csr_rec,
    const int* __restrict__ offs,
    const float* __restrict__ ndst,
    const float* __restrict__ b2,
    float* __restrict__ out) {
    int wid = (blockIdx.x * 256 + threadIdx.x) >> 6;
    int lane = threadIdx.x & 63;
    if (wid >= N_NODES) return;
    int d = wid;
    float res = 0.0f;
    for (int r = 0; r < N_REL; ++r) {
        int e = offs[r * (N_NODES + 1) + d];
        int e1 = offs[r * (N_NODES + 1) + d + 1];
        const int2* rec = csr_rec + (size_t)r * N_EDGES;
        const unsigned short* col = p2b + r * 64 + lane;
        float a = 0.0f;
        for (; e + 7 < e1; e += 8) {
            int sidx[8];
#pragma unroll
            for (int u = 0; u < 8; ++u) sidx[u] = rec[e + u].x;
            unsigned short v[8];
#pragma unroll
            for (int u = 0; u < 8; ++u) v[u] = col[(size_t)sidx[u] * 256];
#pragma unroll
            for (int u = 0; u < 8; ++u) a += bf2f(v[u]);
        }
        for (; e + 3 < e1; e += 4) {
            int sidx[4];
#pragma unroll
            for (int u = 0; u < 4; ++u) sidx[u] = rec[e + u].x;
            unsigned short v[4];
#pragma unroll
            for (int u = 0; u < 4; ++u) v[u] = col[(size_t)sidx[u] * 256];
#pragma unroll
            for (int u = 0; u < 4; ++u) a += bf2f(v[u]);
        }
        for (; e < e1; ++e)
            a += bf2f(col[(size_t)rec[e].x * 256]);
        res += a * ndst[(size_t)r * N_NODES + d];
    }
    res = 0.25f * res + 0.25f * (b2[lane] + b2[64 + lane] + b2[128 + lane] + b2[192 + lane]);
    out[(size_t)d * OUTD + lane] = res;
}

// ----------------------------------------------------------------- launch ---
extern "C" void kernel_launch(void* const* d_in, const int* in_sizes, int n_in,
                              void* d_out, int out_size, void* d_ws, size_t ws_size,
                              hipStream_t stream) {
    const int* src = (const int*)d_in[1];
    const int* dst = (const int*)d_in[2];
    const float* emb = (const float*)d_in[3];
    const float* W1 = (const float*)d_in[4];
    const float* b1 = (const float*)d_in[5];
    const float* W2 = (const float*)d_in[6];
    const float* b2 = (const float*)d_in[7];
    float* out = (float*)d_out;

    char* p = (char*)d_ws;
    auto alloc = [&](size_t bytes) -> void* {
        void* q = (void*)p;
        p += (bytes + 255) & ~(size_t)255;
        return q;
    };
    // ---- persistent (~46 MB)
    int* offs = (int*)alloc((size_t)N_REL * (N_NODES + 1) * 4);
    int* bsum = (int*)alloc((size_t)N_REL * NBLK2 * 4);
    float* nsrc = (float*)alloc((size_t)N_REL * N_NODES * 4);
    float* ndst = (float*)alloc((size_t)N_REL * N_NODES * 4);
    int2* csr_rec = (int2*)alloc((size_t)N_REL * N_EDGES * 8);                // 16 MB
    unsigned short* h1b = (unsigned short*)alloc((size_t)N_NODES * HID * 2);  // 12.8 MB
    unsigned short* embb = (unsigned short*)alloc((size_t)N_NODES * EMB * 2); // 12.8 MB
    unsigned short* W1p = (unsigned short*)alloc((size_t)16 * 8 * 64 * 8 * 2);  // 128 KB
    unsigned short* W2p = (unsigned short*)alloc((size_t)4 * 16 * 64 * 8 * 2);  // 64 KB
    // ---- transient region X: CSR-build buffers, then aggb, then p2b (aliased)
    char* X = p;
    size_t persistent = (size_t)(p - (char*)d_ws);
    unsigned* cnt_dst = (unsigned*)X;                                         // 12.8 MB
    unsigned* cnt_src = cnt_dst + (size_t)SLICES * N_REL * 2 * CHUNKW;        // 12.8 MB
    unsigned short* rank = (unsigned short*)(cnt_src + (size_t)SLICES * N_REL * 2 * CHUNKW); // 4 MB
    unsigned* aggb = (unsigned*)X;              // [N][256] u32, 51.2 MB, after place
    unsigned short* p2b = (unsigned short*)X;   // [N][256] bf16, 25.6 MB, after gemm1

    size_t avail = ws_size > persistent ? ws_size - persistent : 0;
    size_t maxn = avail / ((size_t)N_REL * EMB * 2);
    int npc = (int)(maxn > (size_t)N_NODES ? (size_t)N_NODES : maxn);
    if (npc < 256) npc = 256;

    // one-time conversions/packs (independent of CSR build)
    cvt_kernel<<<(N_NODES * EMB / 4 + 255) / 256, 256, 0, stream>>>(emb, embb);
    packW1_kernel<<<32, 256, 0, stream>>>(W1, W1p);
    packW2_kernel<<<16, 256, 0, stream>>>(W2, W2p);

    // CSR build: LDS histograms (no global atomics, no memset)
    hist_kernel<<<dim3(SLICES, 2, 8), 256, 0, stream>>>(src, dst, cnt_dst, cnt_src, rank);
    scan1_kernel<<<dim3(NBLK2, N_REL), 256, 0, stream>>>(cnt_dst, cnt_src, nsrc, ndst, offs, bsum);
    scan2_kernel<<<N_REL, 256, 0, stream>>>(bsum, offs);
    offs_fin_kernel<<<(N_REL * N_NODES + 255) / 256, 256, 0, stream>>>(bsum, offs);
    dim3 egrid((N_EDGES + 255) / 256, N_REL);
    place_kernel<<<egrid, 256, 0, stream>>>(src, dst, rank, cnt_dst, nsrc, offs, csr_rec);

    // layer 1: embb -> aggb (bf16) -> h1b (MFMA)
    for (int n0 = 0; n0 < N_NODES; n0 += npc) {
        int nn = (N_NODES - n0) < npc ? (N_NODES - n0) : npc;
        gather1_kernel<<<(nn + 3) / 4, 256, 0, stream>>>(embb, csr_rec, offs, ndst, aggb, n0, nn);
    }
    gemm1_mfma<<<(N_NODES + 63) / 64, 256, 0, stream>>>(
        (const unsigned short*)aggb, W1p, b1, h1b, N_NODES);
    // layer 2: h1b -> p2b (MFMA, project-first, bf16) -> out
    gemm2_mfma<<<(N_NODES + 63) / 64, 256, 0, stream>>>(h1b, W2p, nsrc, p2b);
    gather2_kernel<<<(N_NODES * 64 + 255) / 256, 256, 0, stream>>>(
        p2b, csr_rec, offs, ndst, b2, out);
}

// Round 13
// 312.578 us; speedup vs baseline: 3.6485x; 1.0409x over previous
//
#include <hip/hip_runtime.h>
#include <hip/hip_bf16.h>

#define N_NODES 50000
#define N_REL   4
#define N_EDGES 500000
#define EMB     128
#define HID     128
#define OUTD    64
#define SLICES  32
#define EPS     (N_EDGES / SLICES)   // 15625 edges per slice (exact)
#define CHUNKN  25000                // nodes per chunk (2 chunks)
#define CHUNKW  12500                // packed u32 per chunk (2 x u16)
#define NBLK2   98                   // ceil(50000 / 512) scan1 blocks per rel

typedef __attribute__((ext_vector_type(8))) short short8v;   // 8 bf16 = 4 VGPR
typedef __attribute__((ext_vector_type(4))) float float4v;   // mfma acc

__device__ __forceinline__ unsigned short f2bf(float f) {   // RNE bf16 pack
    unsigned u = __float_as_uint(f);
    u = (u + 0x7fffu + ((u >> 16) & 1u)) >> 16;
    return (unsigned short)u;
}
__device__ __forceinline__ float bf2f(unsigned short v) {
    return __uint_as_float(((unsigned)v) << 16);
}

// ---- 0a) cvt: emb fp32 -> bf16 table ---------------------------------------
__global__ void cvt_kernel(const float* __restrict__ in, unsigned short* __restrict__ outb) {
    int i = blockIdx.x * blockDim.x + threadIdx.x;
    if (i >= N_NODES * EMB / 4) return;
    float4 v = *(const float4*)&in[(size_t)i * 4];
    ushort4 o;
    o.x = f2bf(v.x); o.y = f2bf(v.y); o.z = f2bf(v.z); o.w = f2bf(v.w);
    *(ushort4*)&outb[(size_t)i * 4] = o;
}

// ---- 0b) pack W1 [512][128] f32 -> mfma B-fragment order, bf16 -------------
__global__ void packW1_kernel(const float* __restrict__ W1, unsigned short* __restrict__ W1p) {
    int idx = blockIdx.x * blockDim.x + threadIdx.x;
    if (idx >= 16 * 8 * 64) return;
    int l = idx & 63, ct = (idx >> 6) & 7, ks = idx >> 9;
    int n = ct * 16 + (l & 15);
    int k0 = ks * 32 + (l >> 4) * 8;
    ushort4 o0, o1;
    o0.x = f2bf(W1[(size_t)(k0 + 0) * 128 + n]);
    o0.y = f2bf(W1[(size_t)(k0 + 1) * 128 + n]);
    o0.z = f2bf(W1[(size_t)(k0 + 2) * 128 + n]);
    o0.w = f2bf(W1[(size_t)(k0 + 3) * 128 + n]);
    o1.x = f2bf(W1[(size_t)(k0 + 4) * 128 + n]);
    o1.y = f2bf(W1[(size_t)(k0 + 5) * 128 + n]);
    o1.z = f2bf(W1[(size_t)(k0 + 6) * 128 + n]);
    o1.w = f2bf(W1[(size_t)(k0 + 7) * 128 + n]);
    *(ushort4*)&W1p[(size_t)idx * 8]     = o0;
    *(ushort4*)&W1p[(size_t)idx * 8 + 4] = o1;
}

// ---- 0c) pack W2 [4][128][64] -> B-fragments for cols 0..255 ----------------
__global__ void packW2_kernel(const float* __restrict__ W2, unsigned short* __restrict__ W2p) {
    int idx = blockIdx.x * blockDim.x + threadIdx.x;
    if (idx >= 4 * 16 * 64) return;
    int l = idx & 63, ct = (idx >> 6) & 15, ks = idx >> 10;
    int n = ct * 16 + (l & 15);
    int r = n >> 6, cc = n & 63;
    int k0 = ks * 32 + (l >> 4) * 8;
    ushort4 o0, o1;
    o0.x = f2bf(W2[((size_t)r * 128 + k0 + 0) * 64 + cc]);
    o0.y = f2bf(W2[((size_t)r * 128 + k0 + 1) * 64 + cc]);
    o0.z = f2bf(W2[((size_t)r * 128 + k0 + 2) * 64 + cc]);
    o0.w = f2bf(W2[((size_t)r * 128 + k0 + 3) * 64 + cc]);
    o1.x = f2bf(W2[((size_t)r * 128 + k0 + 4) * 64 + cc]);
    o1.y = f2bf(W2[((size_t)r * 128 + k0 + 5) * 64 + cc]);
    o1.z = f2bf(W2[((size_t)r * 128 + k0 + 6) * 64 + cc]);
    o1.w = f2bf(W2[((size_t)r * 128 + k0 + 7) * 64 + cc]);
    *(ushort4*)&W2p[(size_t)idx * 8]     = o0;
    *(ushort4*)&W2p[(size_t)idx * 8 + 4] = o1;
}

// ---- 1) hist: per-slice LDS histograms, NO global atomics ------------------
__global__ __launch_bounds__(256) void hist_kernel(
    const int* __restrict__ src, const int* __restrict__ dst,
    unsigned* __restrict__ cnt_dst, unsigned* __restrict__ cnt_src,
    unsigned short* __restrict__ rank) {
    const int s = blockIdx.x;
    const int ch = blockIdx.y;
    const int z = blockIdx.z;
    const int r = z & 3;
    const bool do_dst = (z < 4);
    const int t = threadIdx.x;
    __shared__ unsigned bins[CHUNKW];          // 50 KB: 25000 x u16 packed
    for (int i = t; i < CHUNKW; i += 256) bins[i] = 0;
    __syncthreads();
    const int* col = do_dst ? dst : src;
    const int c0 = ch * CHUNKN;
    for (int e = s * EPS + t; e < (s + 1) * EPS; e += 256) {
        int d = col[(size_t)r * N_EDGES + e];
        unsigned dl = (unsigned)(d - c0);
        if (dl < CHUNKN) {
            unsigned sh = (dl & 1) * 16;
            unsigned old = atomicAdd(&bins[dl >> 1], 1u << sh);
            if (do_dst)
                rank[(size_t)r * N_EDGES + e] = (unsigned short)((old >> sh) & 0xffffu);
        }
    }
    __syncthreads();
    unsigned* out = (do_dst ? cnt_dst : cnt_src)
                  + (((size_t)s * N_REL + r) * 2 + ch) * CHUNKW;
    for (int i = t; i < CHUNKW; i += 256) out[i] = bins[i];
}

// ---- 2a) scan1 --------------------------------------------------------------
__global__ __launch_bounds__(256) void scan1_kernel(
    unsigned* __restrict__ cnt_dst, const unsigned* __restrict__ cnt_src,
    float* __restrict__ nsrc, float* __restrict__ ndst,
    int* __restrict__ offs, int* __restrict__ bsum) {
    const int r = blockIdx.y;
    const int blk = blockIdx.x;
    const int t = threadIdx.x;
    const int pair = blk * 256 + t;            // 0 .. 24999
    int d0 = 0, d1 = 0;
    if (pair < CHUNKN) {
        int ch = (2 * pair) / CHUNKN;          // 0 or 1
        int i = pair - ch * CHUNKW;
        unsigned run0 = 0, run1 = 0;
#pragma unroll
        for (int s = 0; s < SLICES; ++s) {
            size_t idx = (((size_t)s * N_REL + r) * 2 + ch) * CHUNKW + i;
            unsigned v = cnt_dst[idx];
            cnt_dst[idx] = run0 | (run1 << 16); // exclusive slice-prefix (packed)
            run0 += v & 0xffffu;
            run1 += v >> 16;
        }
        d0 = (int)run0; d1 = (int)run1;
        unsigned s0 = 0, s1 = 0;
#pragma unroll
        for (int s = 0; s < SLICES; ++s) {
            unsigned v = cnt_src[(((size_t)s * N_REL + r) * 2 + ch) * CHUNKW + i];
            s0 += v & 0xffffu;
            s1 += v >> 16;
        }
        size_t nidx = (size_t)r * N_NODES + 2 * pair;
        nsrc[nidx]     = s0 ? rsqrtf((float)s0) : 0.0f;
        nsrc[nidx + 1] = s1 ? rsqrtf((float)s1) : 0.0f;
        ndst[nidx]     = d0 ? rsqrtf((float)d0) : 0.0f;
        ndst[nidx + 1] = d1 ? rsqrtf((float)d1) : 0.0f;
    }
    __shared__ int sh[256];
    int dsum = d0 + d1;
    sh[t] = dsum;
    __syncthreads();
#pragma unroll
    for (int off = 1; off < 256; off <<= 1) {
        int v = (t >= off) ? sh[t - off] : 0;
        __syncthreads();
        sh[t] += v;
        __syncthreads();
    }
    if (pair < CHUNKN) {
        int base = sh[t] - dsum;
        offs[r * (N_NODES + 1) + 2 * pair]     = base;
        offs[r * (N_NODES + 1) + 2 * pair + 1] = base + d0;
    }
    if (t == 255) bsum[r * NBLK2 + blk] = sh[255];
}

// ---- 2b) scan2 --------------------------------------------------------------
__global__ __launch_bounds__(256) void scan2_kernel(int* __restrict__ bsum,
                                                    int* __restrict__ offs) {
    const int r = blockIdx.x;
    const int t = threadIdx.x;
    __shared__ int sh[256];
    int v = (t < NBLK2) ? bsum[r * NBLK2 + t] : 0;
    sh[t] = v;
    __syncthreads();
#pragma unroll
    for (int off = 1; off < 256; off <<= 1) {
        int u = (t >= off) ? sh[t - off] : 0;
        __syncthreads();
        sh[t] += u;
        __syncthreads();
    }
    if (t < NBLK2) bsum[r * NBLK2 + t] = sh[t] - v;
    if (t == 0) offs[r * (N_NODES + 1) + N_NODES] = N_EDGES;
}

// ---- 2c) finalize offs ------------------------------------------------------
__global__ void offs_fin_kernel(const int* __restrict__ bsum, int* __restrict__ offs) {
    int i = blockIdx.x * blockDim.x + threadIdx.x;
    if (i >= N_REL * N_NODES) return;
    int r = i / N_NODES, n = i - r * N_NODES;
    offs[r * (N_NODES + 1) + n] += bsum[r * NBLK2 + (n >> 9)];
}

// ---- 3) place (no atomics) --------------------------------------------------
__global__ void place_kernel(const int* __restrict__ src, const int* __restrict__ dst,
                             const unsigned short* __restrict__ rank,
                             const unsigned* __restrict__ cnt_dst,
                             const float* __restrict__ nsrc,
                             const int* __restrict__ offs, int2* __restrict__ csr_rec) {
    int e = blockIdx.x * blockDim.x + threadIdx.x;
    int r = blockIdx.y;
    if (e >= N_EDGES) return;
    int s = e / EPS;
    int d = dst[(size_t)r * N_EDGES + e];
    int sg = src[(size_t)r * N_EDGES + e];
    int ch = d / CHUNKN;
    int dl = d - ch * CHUNKN;
    unsigned pv = cnt_dst[(((size_t)s * N_REL + r) * 2 + ch) * CHUNKW + (dl >> 1)];
    int base = (int)((pv >> ((dl & 1) * 16)) & 0xffffu);
    int p = offs[r * (N_NODES + 1) + d] + base + (int)rank[(size_t)r * N_EDGES + e];
    csr_rec[(size_t)r * N_EDGES + p] =
        make_int2(sg, __float_as_int(nsrc[(size_t)r * N_NODES + sg]));
}

// ---- 4) gather1: 16 lanes/row (uint4), 4 edges per wave-load ----------------
__global__ __launch_bounds__(256) void gather1_kernel(
    const unsigned short* __restrict__ xb,    // [N][128] bf16
    const int2* __restrict__ csr_rec,
    const int* __restrict__ offs,
    const float* __restrict__ ndst,
    unsigned* __restrict__ aggb,              // [N][256] u32 (= 512 bf16)
    int node0, int nnodes) {
    int wid = (blockIdx.x * 256 + threadIdx.x) >> 6;
    int lane = threadIdx.x & 63;
    if (wid >= nnodes) return;
    int d = node0 + wid;
    const int eg = lane >> 4;                 // edge group 0..3
    const int cs = lane & 15;                 // col segment: bf16 cols cs*8..+7
    const uint4* x4 = (const uint4*)xb;       // row = 16 uint4
    unsigned* arow = aggb + (size_t)wid * (N_REL * 64);
    for (int r = 0; r < N_REL; ++r) {
        int e0 = offs[r * (N_NODES + 1) + d];
        int e1 = offs[r * (N_NODES + 1) + d + 1];
        const int2* rec = csr_rec + (size_t)r * N_EDGES;
        float a[8];
#pragma unroll
        for (int j = 0; j < 8; ++j) a[j] = 0.0f;
        for (int e = e0; e < e1; e += 4) {
            int ee = e + eg;
            bool ok = ee < e1;
            int2 rc = rec[ok ? ee : e0];
            float w = ok ? __int_as_float(rc.y) : 0.0f;
            uint4 v = x4[(size_t)rc.x * 16 + cs];
            a[0] += __uint_as_float(v.x << 16) * w;
            a[1] += __uint_as_float(v.x & 0xffff0000u) * w;
            a[2] += __uint_as_float(v.y << 16) * w;
            a[3] += __uint_as_float(v.y & 0xffff0000u) * w;
            a[4] += __uint_as_float(v.z << 16) * w;
            a[5] += __uint_as_float(v.z & 0xffff0000u) * w;
            a[6] += __uint_as_float(v.w << 16) * w;
            a[7] += __uint_as_float(v.w & 0xffff0000u) * w;
        }
        // combine the 4 edge groups (lane bits 4,5)
#pragma unroll
        for (int j = 0; j < 8; ++j) {
            a[j] += __shfl_xor(a[j], 16, 64);
            a[j] += __shfl_xor(a[j], 32, 64);
        }
        float sc = 0.25f * ndst[(size_t)r * N_NODES + d];
        if (eg == 0) {
            uint4 o;
            o.x = (unsigned)f2bf(a[0] * sc) | ((unsigned)f2bf(a[1] * sc) << 16);
            o.y = (unsigned)f2bf(a[2] * sc) | ((unsigned)f2bf(a[3] * sc) << 16);
            o.z = (unsigned)f2bf(a[4] * sc) | ((unsigned)f2bf(a[5] * sc) << 16);
            o.w = (unsigned)f2bf(a[6] * sc) | ((unsigned)f2bf(a[7] * sc) << 16);
            *(uint4*)&arow[r * 64 + cs * 4] = o;
        }
    }
}

// ---- 5) gemm1 MFMA: h1b = aggb[.][512](bf16) @ W1p + bias -> bf16 -----------
__global__ __launch_bounds__(256) void gemm1_mfma(
    const unsigned short* __restrict__ aggb,  // [N][512] bf16
    const unsigned short* __restrict__ W1p,   // packed fragments
    const float* __restrict__ b1,
    unsigned short* __restrict__ h1b,         // [N][128] bf16
    int nnodes) {
    const int t = threadIdx.x;
    const int w = t >> 6, l = t & 63;
    const int row_base = blockIdx.x * 64 + w * 16;
    const int m = l & 15, kg = l >> 4;
    float4v acc[8];
#pragma unroll
    for (int ct = 0; ct < 8; ++ct) acc[ct] = (float4v){0.f, 0.f, 0.f, 0.f};
    const int arow = row_base + m;
    const bool aok = (arow < nnodes);
    const short8v* ap = (const short8v*)(aggb + (size_t)arow * 512 + kg * 8);
    const short8v* bp = (const short8v*)W1p;
#pragma unroll
    for (int ks = 0; ks < 16; ++ks) {
        short8v a = (short8v){0,0,0,0,0,0,0,0};
        if (aok) a = ap[ks * 4];               // +32 bf16 per ks
#pragma unroll
        for (int ct = 0; ct < 8; ++ct) {
            short8v b = bp[(ks * 8 + ct) * 64 + l];
            acc[ct] = __builtin_amdgcn_mfma_f32_16x16x32_bf16(a, b, acc[ct], 0, 0, 0);
        }
    }
    const int orow0 = row_base + kg * 4;
#pragma unroll
    for (int ct = 0; ct < 8; ++ct) {
        int c = ct * 16 + m;
        float bias = 0.25f * (b1[c] + b1[128 + c] + b1[256 + c] + b1[384 + c]);
#pragma unroll
        for (int i = 0; i < 4; ++i) {
            int row = orow0 + i;
            if (row < nnodes)
                h1b[(size_t)row * 128 + c] = f2bf(acc[ct][i] + bias);
        }
    }
}

// ---- 6) gemm2 MFMA: p2b = rowscale(h1b[.][128] @ W2p) -> bf16 ---------------
__global__ __launch_bounds__(256) void gemm2_mfma(
    const unsigned short* __restrict__ h1b,   // [N][128] bf16
    const unsigned short* __restrict__ W2p,   // packed fragments
    const float* __restrict__ nsrc,           // [4][N]
    unsigned short* __restrict__ p2b) {       // [N][256] bf16
    const int t = threadIdx.x;
    const int w = t >> 6, l = t & 63;
    const int row_base = blockIdx.x * 64 + w * 16;
    const int m = l & 15, kg = l >> 4;
    float4v acc[16];
#pragma unroll
    for (int ct = 0; ct < 16; ++ct) acc[ct] = (float4v){0.f, 0.f, 0.f, 0.f};
    const int arow = row_base + m;
    const bool aok = (arow < N_NODES);
    const short8v* ap = (const short8v*)(h1b + (size_t)arow * 128 + kg * 8);
    const short8v* bp = (const short8v*)W2p;
#pragma unroll
    for (int ks = 0; ks < 4; ++ks) {
        short8v a = (short8v){0,0,0,0,0,0,0,0};
        if (aok) a = ap[ks * 4];
#pragma unroll
        for (int ct = 0; ct < 16; ++ct) {
            short8v b = bp[(ks * 16 + ct) * 64 + l];
            acc[ct] = __builtin_amdgcn_mfma_f32_16x16x32_bf16(a, b, acc[ct], 0, 0, 0);
        }
    }
    const int orow0 = row_base + kg * 4;
#pragma unroll
    for (int ct = 0; ct < 16; ++ct) {
        int c = ct * 16 + m;
        int r = c >> 6;
#pragma unroll
        for (int i = 0; i < 4; ++i) {
            int row = orow0 + i;
            if (row < N_NODES)
                p2b[(size_t)row * 256 + c] = f2bf(acc[ct][i] * nsrc[(size_t)r * N_NODES + row]);
        }
    }
}

// ---- 7) gather2: 8 lanes/slice (uint4), 8 edges per wave-load ---------------
__global__ __launch_bounds__(256) void gather2_kernel(
    const unsigned short* __restrict__ p2b,   // [N][256] bf16
    const int2* __restrict__ csr_rec,
    const int* __restrict__ offs,
    const float* __restrict__ ndst,
    const float* __restrict__ b2,
    float* __restrict__ out) {
    int wid = (blockIdx.x * 256 + threadIdx.x) >> 6;
    int lane = threadIdx.x & 63;
    if (wid >= N_NODES) return;
    int d = wid;
    const int eg = lane >> 3;                 // edge group 0..7
    const int cs = lane & 7;                  // bf16 cols cs*8..+7 of 64-col slice
    const uint4* p4 = (const uint4*)p2b;      // row = 32 uint4
    float tot[8];
#pragma unroll
    for (int j = 0; j < 8; ++j) tot[j] = 0.0f;
    for (int r = 0; r < N_REL; ++r) {
        int e0 = offs[r * (N_NODES + 1) + d];
        int e1 = offs[r * (N_NODES + 1) + d + 1];
        const int2* rec = csr_rec + (size_t)r * N_EDGES;
        float a[8];
#pragma unroll
        for (int j = 0; j < 8; ++j) a[j] = 0.0f;
        for (int e = e0; e < e1; e += 8) {
            int ee = e + eg;
            bool ok = ee < e1;
            int2 rc = rec[ok ? ee : e0];
            float w = ok ? 1.0f : 0.0f;
            uint4 v = p4[(size_t)rc.x * 32 + r * 8 + cs];
            a[0] += __uint_as_float(v.x << 16) * w;
            a[1] += __uint_as_float(v.x & 0xffff0000u) * w;
            a[2] += __uint_as_float(v.y << 16) * w;
            a[3] += __uint_as_float(v.y & 0xffff0000u) * w;
            a[4] += __uint_as_float(v.z << 16) * w;
            a[5] += __uint_as_float(v.z & 0xffff0000u) * w;
            a[6] += __uint_as_float(v.w << 16) * w;
            a[7] += __uint_as_float(v.w & 0xffff0000u) * w;
        }
        float nd = ndst[(size_t)r * N_NODES + d];
#pragma unroll
        for (int j = 0; j < 8; ++j) tot[j] += a[j] * nd;
    }
    // combine the 8 edge groups (lane bits 3,4,5)
#pragma unroll
    for (int j = 0; j < 8; ++j) {
        tot[j] += __shfl_xor(tot[j], 8, 64);
        tot[j] += __shfl_xor(tot[j], 16, 64);
        tot[j] += __shfl_xor(tot[j], 32, 64);
    }
    if (eg == 0) {
        float o[8];
#pragma unroll
        for (int j = 0; j < 8; ++j) {
            int c = cs * 8 + j;
            o[j] = 0.25f * tot[j]
                 + 0.25f * (b2[c] + b2[64 + c] + b2[128 + c] + b2[192 + c]);
        }
        *(float4*)&out[(size_t)d * OUTD + cs * 8]     = *(float4*)&o[0];
        *(float4*)&out[(size_t)d * OUTD + cs * 8 + 4] = *(float4*)&o[4];
    }
}

// ----------------------------------------------------------------- launch ---
extern "C" void kernel_launch(void* const* d_in, const int* in_sizes, int n_in,
                              void* d_out, int out_size, void* d_ws, size_t ws_size,
                              hipStream_t stream) {
    const int* src = (const int*)d_in[1];
    const int* dst = (const int*)d_in[2];
    const float* emb = (const float*)d_in[3];
    const float* W1 = (const float*)d_in[4];
    const float* b1 = (const float*)d_in[5];
    const float* W2 = (const float*)d_in[6];
    const float* b2 = (const float*)d_in[7];
    float* out = (float*)d_out;

    char* p = (char*)d_ws;
    auto alloc = [&](size_t bytes) -> void* {
        void* q = (void*)p;
        p += (bytes + 255) & ~(size_t)255;
        return q;
    };
    // ---- persistent (~46 MB)
    int* offs = (int*)alloc((size_t)N_REL * (N_NODES + 1) * 4);
    int* bsum = (int*)alloc((size_t)N_REL * NBLK2 * 4);
    float* nsrc = (float*)alloc((size_t)N_REL * N_NODES * 4);
    float* ndst = (float*)alloc((size_t)N_REL * N_NODES * 4);
    int2* csr_rec = (int2*)alloc((size_t)N_REL * N_EDGES * 8);                // 16 MB
    unsigned short* h1b = (unsigned short*)alloc((size_t)N_NODES * HID * 2);  // 12.8 MB
    unsigned short* embb = (unsigned short*)alloc((size_t)N_NODES * EMB * 2); // 12.8 MB
    unsigned short* W1p = (unsigned short*)alloc((size_t)16 * 8 * 64 * 8 * 2);  // 128 KB
    unsigned short* W2p = (unsigned short*)alloc((size_t)4 * 16 * 64 * 8 * 2);  // 64 KB
    // ---- transient region X: CSR-build buffers, then aggb, then p2b (aliased)
    char* X = p;
    size_t persistent = (size_t)(p - (char*)d_ws);
    unsigned* cnt_dst = (unsigned*)X;                                         // 12.8 MB
    unsigned* cnt_src = cnt_dst + (size_t)SLICES * N_REL * 2 * CHUNKW;        // 12.8 MB
    unsigned short* rank = (unsigned short*)(cnt_src + (size_t)SLICES * N_REL * 2 * CHUNKW); // 4 MB
    unsigned* aggb = (unsigned*)X;              // [N][256] u32, 51.2 MB, after place
    unsigned short* p2b = (unsigned short*)X;   // [N][256] bf16, 25.6 MB, after gemm1

    size_t avail = ws_size > persistent ? ws_size - persistent : 0;
    size_t maxn = avail / ((size_t)N_REL * EMB * 2);
    int npc = (int)(maxn > (size_t)N_NODES ? (size_t)N_NODES : maxn);
    if (npc < 256) npc = 256;

    // one-time conversions/packs (independent of CSR build)
    cvt_kernel<<<(N_NODES * EMB / 4 + 255) / 256, 256, 0, stream>>>(emb, embb);
    packW1_kernel<<<32, 256, 0, stream>>>(W1, W1p);
    packW2_kernel<<<16, 256, 0, stream>>>(W2, W2p);

    // CSR build: LDS histograms (no global atomics, no memset)
    hist_kernel<<<dim3(SLICES, 2, 8), 256, 0, stream>>>(src, dst, cnt_dst, cnt_src, rank);
    scan1_kernel<<<dim3(NBLK2, N_REL), 256, 0, stream>>>(cnt_dst, cnt_src, nsrc, ndst, offs, bsum);
    scan2_kernel<<<N_REL, 256, 0, stream>>>(bsum, offs);
    offs_fin_kernel<<<(N_REL * N_NODES + 255) / 256, 256, 0, stream>>>(bsum, offs);
    dim3 egrid((N_EDGES + 255) / 256, N_REL);
    place_kernel<<<egrid, 256, 0, stream>>>(src, dst, rank, cnt_dst, nsrc, offs, csr_rec);

    // layer 1: embb -> aggb (bf16) -> h1b (MFMA)
    for (int n0 = 0; n0 < N_NODES; n0 += npc) {
        int nn = (N_NODES - n0) < npc ? (N_NODES - n0) : npc;
        gather1_kernel<<<(nn + 3) / 4, 256, 0, stream>>>(embb, csr_rec, offs, ndst, aggb, n0, nn);
    }
    gemm1_mfma<<<(N_NODES + 63) / 64, 256, 0, stream>>>(
        (const unsigned short*)aggb, W1p, b1, h1b, N_NODES);
    // layer 2: h1b -> p2b (MFMA, project-first, bf16) -> out
    gemm2_mfma<<<(N_NODES + 63) / 64, 256, 0, stream>>>(h1b, W2p, nsrc, p2b);
    gather2_kernel<<<(N_NODES * 64 + 255) / 256, 256, 0, stream>>>(
        p2b, csr_rec, offs, ndst, b2, out);
}